// Round 2
// baseline (307.183 us; speedup 1.0000x reference)
//
#include <hip/hip_runtime.h>

typedef unsigned short u16;

#define B_   2
#define T_   5
#define N_   4096
#define C_   16
#define D_   128
#define S_   4
#define NS_  16384   // (T-1)*N
#define M_   8192    // B*N
#define EPS_ 1e-5f

// ---- ws layout (fp32 element offsets) ----
#define XF_OFF    0u         // converted x: 655360 floats
#define WF_OFF    655360u    // converted weights: 52912 floats (padded)
#define H_OFF     708608u    // h: M*512
#define HMAX_OFF  4902912u   // hmax: M*128
#define Y_OFF     5951488u   // y: 3*M*128
#define ST_OFF    9097216u   // stats: 2048 floats (+flag at +2048)
#define FLAG_OFF  (ST_OFF + 2048u)

// weight offsets within WF (padded to 16-float alignment)
#define W_CONV   0
#define W_CONVB  2048
#define W_BNG    2176
#define W_BNB    2304
#define W_FC1    2432
#define W_FC1B   18816
#define W_CE     18944
#define W_CEB    19328
#define W_FC2    19344
#define W_FC2B   35728
#define W_LWH    35856
#define W_LWHB   36240
#define W_FC3    36256
#define W_FC3B   52640
#define W_TH     52768
#define W_THB    52896
#define W_TOTAL  52912

#define OUT_FEAT 57344       // element offset of feature within d_out

// st layout: [0..127] sum_h, [128..255] sumsq_h, [256..383] scale1, [384..511] shift1
// branch k (0..2): base=512+k*512: +0 sum, +128 sumsq, +256 scale, +384 shift

__device__ __forceinline__ float bf2f(u16 u) { return __uint_as_float(((unsigned)u) << 16); }
__device__ __forceinline__ u16 f2bf(float f) {
    unsigned u = __float_as_uint(f);
    return (u16)((u + 0x7fffu + ((u >> 16) & 1u)) >> 16);
}

struct P16 { const void* p[16]; };

__global__ void k_zero(float* __restrict__ st) {
    st[blockIdx.x * 256 + threadIdx.x] = 0.0f;
}

// Detect input dtype: fp32 N(0,1) words are small; bf16 pairs reinterpreted as
// fp32 have exponent bits from bf16 exponents -> ~2^125. flag=1 -> fp32.
__global__ __launch_bounds__(64) void k_detect(const void* __restrict__ x, float* __restrict__ flag) {
    int lane = threadIdx.x;
    float v = fabsf(((const float*)x)[lane]);   // 256 bytes, in-bounds either dtype
    #pragma unroll
    for (int off = 32; off > 0; off >>= 1) v = fmaxf(v, __shfl_xor(v, off));
    if (lane == 0) *flag = (v < 1e4f) ? 1.0f : 0.0f;
}

__global__ __launch_bounds__(256) void k_convert_x(const void* __restrict__ x,
                                                   const float* __restrict__ flag,
                                                   float* __restrict__ xf) {
    int i = blockIdx.x * 256 + threadIdx.x;     // grid covers 655360 exactly
    bool isf = (*flag != 0.0f);
    xf[i] = isf ? ((const float*)x)[i] : bf2f(((const u16*)x)[i]);
}

__global__ __launch_bounds__(256) void k_convert_w(P16 ps, const float* __restrict__ flag,
                                                   float* __restrict__ wf) {
    const int offs[16]  = {W_CONV, W_CONVB, W_BNG, W_BNB, W_FC1, W_FC1B, W_CE, W_CEB,
                           W_FC2, W_FC2B, W_LWH, W_LWHB, W_FC3, W_FC3B, W_TH, W_THB};
    const int sizes[16] = {2048, 128, 128, 128, 16384, 128, 384, 3,
                           16384, 128, 384, 3, 16384, 128, 128, 1};
    int e = blockIdx.x * 256 + threadIdx.x;
    if (e >= W_TOTAL) return;
    bool isf = (*flag != 0.0f);
    int k = 0;
    #pragma unroll
    for (int i = 1; i < 16; i++) if (e >= offs[i]) k = i;
    int r = e - offs[k];
    float v = 0.0f;
    if (r < sizes[k])
        v = isf ? ((const float*)ps.p[k])[r] : bf2f(((const u16*)ps.p[k])[r]);
    wf[e] = v;
}

// Ball query (first-4-by-index within radius) + gather + conv1. One wave per query.
__global__ __launch_bounds__(64) void k_ballconv(const float* __restrict__ xf,
                                                 const float* __restrict__ wf,
                                                 float* __restrict__ h) {
    int m = blockIdx.x;
    int b = m >> 12, q = m & (N_ - 1);
    int lane = threadIdx.x;
    const float* xb = xf + (size_t)b * (T_ * N_ * C_);
    float qx = xb[q * C_ + 0];
    float qy = xb[q * C_ + 1];
    float qz = xb[q * C_ + 2];
    float qn = (qx * qx + qy * qy) + qz * qz;
    const float* pts = xb + N_ * C_;  // x[b,1:,:,:]: 16384 rows of 16

    int i0 = 0, i1 = 0, i2 = 0, i3 = 0;
    int cnt = 0;
    for (int base = 0; base < NS_ && cnt < 4; base += 64) {
        int j = base + lane;
        float4 pv = *reinterpret_cast<const float4*>(pts + (size_t)j * C_);
        float pn = (pv.x * pv.x + pv.y * pv.y) + pv.z * pv.z;
        float dot = (qx * pv.x + qy * pv.y) + qz * pv.z;
        float d2 = (qn + pn) - 2.0f * dot;   // match reference's algebraic form
        unsigned long long mask = __ballot(d2 < 1.0f);
        while (mask && cnt < 4) {            // uniform across the wave
            int jj = base + __builtin_ctzll(mask);
            if (cnt == 0) i0 = jj; else if (cnt == 1) i1 = jj;
            else if (cnt == 2) i2 = jj; else i3 = jj;
            cnt++;
            mask &= (mask - 1);
        }
    }
    if (cnt >= 1) {                          // duplicate-first fill
        if (cnt <= 1) i1 = i0;
        if (cnt <= 2) i2 = i0;
        if (cnt <= 3) i3 = i0;
    }

    __shared__ float g[S_][C_];
    {
        int s = lane >> 4, c = lane & 15;
        int id = (s == 0) ? i0 : (s == 1) ? i1 : (s == 2) ? i2 : i3;
        float gv = 0.0f;
        if (cnt > 0) gv = pts[(size_t)id * C_ + c];
        g[s][c] = gv;                        // empty query -> grouped=0, h=bias
    }
    __syncthreads();

    float* hrow = h + (size_t)m * (D_ * S_);
    #pragma unroll
    for (int r = 0; r < 2; r++) {
        int o = lane + 64 * r;
        float wc[C_];
        #pragma unroll
        for (int c = 0; c < C_; c++) wc[c] = wf[W_CONV + o * C_ + c];
        float bo = wf[W_CONVB + o];
        float a[4];
        #pragma unroll
        for (int s = 0; s < S_; s++) {
            float acc = bo;
            #pragma unroll
            for (int c = 0; c < C_; c++) acc += wc[c] * g[s][c];
            a[s] = acc;
        }
        *reinterpret_cast<float4*>(hrow + o * 4) = make_float4(a[0], a[1], a[2], a[3]);
    }
}

// Per-channel sum/sumsq of h over (m,s). 64 blocks x 512 threads; t = o*4+s.
__global__ __launch_bounds__(512) void k_bn1stats(const float* __restrict__ h,
                                                  float* __restrict__ st) {
    int t = threadIdx.x;
    float sum = 0.0f, sq = 0.0f;
    for (int m = blockIdx.x; m < M_; m += gridDim.x) {
        float v = h[(size_t)m * 512 + t];
        sum += v; sq += v * v;
    }
    __shared__ float sm[512];
    sm[t] = sum;
    __syncthreads();
    if (t < 128) atomicAdd(&st[t], sm[4 * t] + sm[4 * t + 1] + sm[4 * t + 2] + sm[4 * t + 3]);
    __syncthreads();
    sm[t] = sq;
    __syncthreads();
    if (t < 128) atomicAdd(&st[128 + t], sm[4 * t] + sm[4 * t + 1] + sm[4 * t + 2] + sm[4 * t + 3]);
}

__global__ void k_bn1fin(float* __restrict__ st, const float* __restrict__ wf) {
    int o = threadIdx.x;
    float mean = st[o] * (1.0f / 32768.0f);
    float var = st[128 + o] * (1.0f / 32768.0f) - mean * mean;
    float sc = wf[W_BNG + o] / sqrtf(fmaxf(var, 0.0f) + EPS_);
    st[256 + o] = sc;
    st[384 + o] = wf[W_BNB + o] - mean * sc;
}

// bn + max over s -> hmax (fp32 ws) and feature (dtype per flag) to d_out
__global__ __launch_bounds__(128) void k_maxfeat(const float* __restrict__ h,
                                                 const float* __restrict__ st,
                                                 float* __restrict__ hmax,
                                                 void* __restrict__ outbase,
                                                 const float* __restrict__ flag) {
    int m = blockIdx.x, o = threadIdx.x;
    float4 v = *reinterpret_cast<const float4*>(h + (size_t)m * 512 + o * 4);
    float sc = st[256 + o], sh = st[384 + o];
    float r = fmaxf(fmaxf(v.x * sc + sh, v.y * sc + sh), fmaxf(v.z * sc + sh, v.w * sc + sh));
    hmax[(size_t)m * D_ + o] = r;
    size_t idx = (size_t)OUT_FEAT + (size_t)m * D_ + o;
    if (*flag != 0.0f) ((float*)outbase)[idx] = r;
    else               ((u16*)outbase)[idx] = f2bf(r);
}

// Three 128x128 FCs, 8 rows of m per block, fused per-channel sum/sumsq atomics.
__global__ __launch_bounds__(128) void k_fc(const float* __restrict__ hmax,
                                            const float* __restrict__ wf,
                                            float* __restrict__ y, float* __restrict__ st) {
    int o = threadIdx.x;
    int m0 = blockIdx.x * 8;
    __shared__ float hs[8][128];
    for (int i = o; i < 8 * 128; i += 128) hs[i >> 7][i & 127] = hmax[(size_t)m0 * 128 + i];
    __syncthreads();

    const int woff[3] = {W_FC1, W_FC2, W_FC3};
    const int boff[3] = {W_FC1B, W_FC2B, W_FC3B};
    #pragma unroll
    for (int k = 0; k < 3; k++) {
        float acc[8];
        float bb = wf[boff[k] + o];
        #pragma unroll
        for (int mm = 0; mm < 8; mm++) acc[mm] = bb;
        const float* wr = wf + woff[k] + o * 128;
        for (int c = 0; c < 128; c += 4) {
            float4 w4 = *reinterpret_cast<const float4*>(wr + c);
            #pragma unroll
            for (int mm = 0; mm < 8; mm++) {
                acc[mm] += w4.x * hs[mm][c + 0];
                acc[mm] += w4.y * hs[mm][c + 1];
                acc[mm] += w4.z * hs[mm][c + 2];
                acc[mm] += w4.w * hs[mm][c + 3];
            }
        }
        float s = 0.0f, sq = 0.0f;
        float* yk = y + (size_t)k * M_ * 128;
        #pragma unroll
        for (int mm = 0; mm < 8; mm++) {
            float v = acc[mm];
            yk[(size_t)(m0 + mm) * 128 + o] = v;
            s += v; sq += v * v;
        }
        int base = 512 + k * 512;
        atomicAdd(&st[base + o], s);
        atomicAdd(&st[base + 128 + o], sq);
    }
}

__global__ void k_bnbfin(float* __restrict__ st, const float* __restrict__ wf) {
    int t = threadIdx.x;  // 0..383
    int k = t >> 7, o = t & 127;
    int base = 512 + k * 512;
    float mean = st[base + o] * (1.0f / 8192.0f);
    float var = st[base + 128 + o] * (1.0f / 8192.0f) - mean * mean;
    float sc = wf[W_BNG + o] / sqrtf(fmaxf(var, 0.0f) + EPS_);
    st[base + 256 + o] = sc;
    st[base + 384 + o] = wf[W_BNB + o] - mean * sc;
}

// bn + relu on y1/y2/y3, tiny head matmuls, 7 outputs per row. One wave per m.
__global__ __launch_bounds__(64) void k_heads(const float* __restrict__ y,
                                              const float* __restrict__ st,
                                              const float* __restrict__ wf,
                                              void* __restrict__ outbase,
                                              const float* __restrict__ flag) {
    int m = blockIdx.x, lane = threadIdx.x;
    const float* y1 = y;
    const float* y2 = y + (size_t)M_ * D_;
    const float* y3 = y + 2 * (size_t)M_ * D_;
    float p[7] = {0, 0, 0, 0, 0, 0, 0};
    #pragma unroll
    for (int cc = 0; cc < 2; cc++) {
        int c = lane + 64 * cc;
        float v1 = fmaxf(y1[(size_t)m * D_ + c] * st[768 + c] + st[896 + c], 0.0f);
        float v2 = fmaxf(y2[(size_t)m * D_ + c] * st[1280 + c] + st[1408 + c], 0.0f);
        float v3 = fmaxf(y3[(size_t)m * D_ + c] * st[1792 + c] + st[1920 + c], 0.0f);
        p[0] += v1 * wf[W_CE + c];
        p[1] += v1 * wf[W_CE + 128 + c];
        p[2] += v1 * wf[W_CE + 256 + c];
        p[3] += v2 * wf[W_LWH + c];
        p[4] += v2 * wf[W_LWH + 128 + c];
        p[5] += v2 * wf[W_LWH + 256 + c];
        p[6] += v3 * wf[W_TH + c];
    }
    #pragma unroll
    for (int off = 32; off > 0; off >>= 1) {
        #pragma unroll
        for (int i = 0; i < 7; i++) p[i] += __shfl_xor(p[i], off);
    }
    if (lane == 0) {
        float o0 = p[0] + wf[W_CEB + 0];
        float o1 = p[1] + wf[W_CEB + 1];
        float o2 = p[2] + wf[W_CEB + 2];
        float o3 = p[3] + wf[W_LWHB + 0];
        float o4 = p[4] + wf[W_LWHB + 1];
        float o5 = p[5] + wf[W_LWHB + 2];
        float o6 = p[6] + wf[W_THB];
        if (*flag != 0.0f) {
            float* po = (float*)outbase;
            po[m * 7 + 0] = o0; po[m * 7 + 1] = o1; po[m * 7 + 2] = o2;
            po[m * 7 + 3] = o3; po[m * 7 + 4] = o4; po[m * 7 + 5] = o5;
            po[m * 7 + 6] = o6;
        } else {
            u16* po = (u16*)outbase;
            po[m * 7 + 0] = f2bf(o0); po[m * 7 + 1] = f2bf(o1); po[m * 7 + 2] = f2bf(o2);
            po[m * 7 + 3] = f2bf(o3); po[m * 7 + 4] = f2bf(o4); po[m * 7 + 5] = f2bf(o5);
            po[m * 7 + 6] = f2bf(o6);
        }
    }
}

extern "C" void kernel_launch(void* const* d_in, const int* in_sizes, int n_in,
                              void* d_out, int out_size, void* d_ws, size_t ws_size,
                              hipStream_t stream) {
    (void)in_sizes; (void)n_in; (void)out_size; (void)ws_size;
    float* ws   = (float*)d_ws;
    float* xf   = ws + XF_OFF;
    float* wf   = ws + WF_OFF;
    float* h    = ws + H_OFF;
    float* hmax = ws + HMAX_OFF;
    float* y    = ws + Y_OFF;
    float* st   = ws + ST_OFF;
    float* flag = ws + FLAG_OFF;

    P16 ps;
    for (int i = 0; i < 16; i++) ps.p[i] = d_in[i + 1];

    hipLaunchKernelGGL(k_zero,      dim3(8),    dim3(256), 0, stream, st);
    hipLaunchKernelGGL(k_detect,    dim3(1),    dim3(64),  0, stream, d_in[0], flag);
    hipLaunchKernelGGL(k_convert_x, dim3(2560), dim3(256), 0, stream, d_in[0], flag, xf);
    hipLaunchKernelGGL(k_convert_w, dim3(207),  dim3(256), 0, stream, ps, flag, wf);
    hipLaunchKernelGGL(k_ballconv,  dim3(M_),   dim3(64),  0, stream, xf, wf, h);
    hipLaunchKernelGGL(k_bn1stats,  dim3(64),   dim3(512), 0, stream, h, st);
    hipLaunchKernelGGL(k_bn1fin,    dim3(1),    dim3(128), 0, stream, st, wf);
    hipLaunchKernelGGL(k_maxfeat,   dim3(M_),   dim3(128), 0, stream, h, st, hmax, d_out, flag);
    hipLaunchKernelGGL(k_fc,        dim3(M_/8), dim3(128), 0, stream, hmax, wf, y, st);
    hipLaunchKernelGGL(k_bnbfin,    dim3(1),    dim3(384), 0, stream, st, wf);
    hipLaunchKernelGGL(k_heads,     dim3(M_),   dim3(64),  0, stream, y, st, wf, d_out, flag);
}

// Round 4
// 257.488 us; speedup vs baseline: 1.1930x; 1.1930x over previous
//
#include <hip/hip_runtime.h>

typedef unsigned short u16;

#define B_   2
#define T_   5
#define N_   4096
#define C_   16
#define D_   128
#define S_   4
#define NS_  16384   // (T-1)*N
#define M_   8192    // B*N
#define EPS_ 1e-5f

// ---- ws layout (fp32 element offsets) ----
#define XF_OFF    0u         // converted x: 655360 floats
#define WF_OFF    655360u    // converted weights: 52912 floats (padded region)
#define H_OFF     708608u    // h: M*512 = 4194304
#define Y_OFF     4902912u   // y: 3*M*128 = 3145728
#define ST_OFF    8048640u   // stats: 2048 floats
#define FLAG_OFF  (ST_OFF + 2048u)

// weight offsets within WF
#define W_CONV   0
#define W_CONVB  2048
#define W_BNG    2176
#define W_BNB    2304
#define W_FC1    2432
#define W_FC1B   18816
#define W_CE     18944
#define W_CEB    19328
#define W_FC2    19344
#define W_FC2B   35728
#define W_LWH    35856
#define W_LWHB   36240
#define W_FC3    36256
#define W_FC3B   52640
#define W_TH     52768
#define W_THB    52896
#define W_TOTAL  52912

#define OUT_FEAT 57344       // element offset of feature within d_out

// st layout: [0..127] sum_h, [128..255] sumsq_h, [256..383] scale1, [384..511] shift1
// branch k (0..2): base=512+k*512: +0 sum, +128 sumsq, +256 scale, +384 shift

__device__ __forceinline__ float bf2f(u16 u) { return __uint_as_float(((unsigned)u) << 16); }
__device__ __forceinline__ u16 f2bf(float f) {
    unsigned u = __float_as_uint(f);
    return (u16)((u + 0x7fffu + ((u >> 16) & 1u)) >> 16);
}

struct P16 { const void* p[16]; };

// 1 WG: zero the 2048-float stats region + detect input dtype.
// fp32 N(0,1) words are small; bf16 pairs reinterpreted as fp32 -> ~2^125.
__global__ __launch_bounds__(256) void k_init(const void* __restrict__ x,
                                              float* __restrict__ st,
                                              float* __restrict__ flag) {
    int tid = threadIdx.x;
    #pragma unroll
    for (int i = 0; i < 8; i++) st[tid + 256 * i] = 0.0f;
    if (tid < 64) {
        float v = fabsf(((const float*)x)[tid]);   // 256 B, in-bounds either dtype
        #pragma unroll
        for (int off = 32; off > 0; off >>= 1) v = fmaxf(v, __shfl_xor(v, off));
        if (tid == 0) *flag = (v < 1e4f) ? 1.0f : 0.0f;
    }
}

// 512 WG x 256: convert x (vectorized, 163840 float4-groups) + all weights.
__global__ __launch_bounds__(256) void k_convert(const void* __restrict__ x, P16 ps,
                                                 const float* __restrict__ flag,
                                                 float* __restrict__ xf,
                                                 float* __restrict__ wf) {
    int gid = blockIdx.x * 256 + threadIdx.x;   // 0..131071
    bool isf = (*flag != 0.0f);
    for (int i = gid; i < 163840; i += 131072) {
        float4 v;
        if (isf) {
            v = ((const float4*)x)[i];
        } else {
            ushort4 u = ((const ushort4*)x)[i];
            v = make_float4(bf2f(u.x), bf2f(u.y), bf2f(u.z), bf2f(u.w));
        }
        ((float4*)xf)[i] = v;
    }
    if (gid < W_TOTAL) {
        const int offs[16]  = {W_CONV, W_CONVB, W_BNG, W_BNB, W_FC1, W_FC1B, W_CE, W_CEB,
                               W_FC2, W_FC2B, W_LWH, W_LWHB, W_FC3, W_FC3B, W_TH, W_THB};
        const int sizes[16] = {2048, 128, 128, 128, 16384, 128, 384, 3,
                               16384, 128, 384, 3, 16384, 128, 128, 1};
        int k = 0;
        #pragma unroll
        for (int i = 1; i < 16; i++) if (gid >= offs[i]) k = i;
        int r = gid - offs[k];
        float v = 0.0f;
        if (r < sizes[k])
            v = isf ? ((const float*)ps.p[k])[r] : bf2f(((const u16*)ps.p[k])[r]);
        wf[gid] = v;
    }
}

// 1024 WG x 256 (4 waves). Each wave: 2 queries (ball query first-4 + gather +
// conv1). Fused per-channel bn1 sum/sumsq: register accum -> LDS -> atomics.
__global__ __launch_bounds__(256) void k_ballconv(const float* __restrict__ xf,
                                                  const float* __restrict__ wf,
                                                  float* __restrict__ h,
                                                  float* __restrict__ st) {
    int tid = threadIdx.x;
    int wave = tid >> 6, lane = tid & 63;
    __shared__ float g[4][S_][C_];       // per-wave gather tile
    __shared__ float red[2][512];        // block stats reduce [sum|sq][wave*128+ch]
    float acc_sum[2] = {0.0f, 0.0f};     // channels lane, lane+64
    float acc_sq[2]  = {0.0f, 0.0f};

    for (int qi = 0; qi < 2; qi++) {
        int m = blockIdx.x * 8 + wave * 2 + qi;
        int b = m >> 12, q = m & (N_ - 1);
        const float* xb = xf + (size_t)b * (T_ * N_ * C_);
        float qx = xb[q * C_ + 0];
        float qy = xb[q * C_ + 1];
        float qz = xb[q * C_ + 2];
        float qn = (qx * qx + qy * qy) + qz * qz;
        const float* pts = xb + N_ * C_;

        int i0 = 0, i1 = 0, i2 = 0, i3 = 0;
        int cnt = 0;
        for (int base = 0; base < NS_ && cnt < 4; base += 64) {
            int j = base + lane;
            float4 pv = *reinterpret_cast<const float4*>(pts + (size_t)j * C_);
            float pn = (pv.x * pv.x + pv.y * pv.y) + pv.z * pv.z;
            float dot = (qx * pv.x + qy * pv.y) + qz * pv.z;
            float d2 = (qn + pn) - 2.0f * dot;      // reference's algebraic form
            unsigned long long mask = __ballot(d2 < 1.0f);
            while (mask && cnt < 4) {               // wave-uniform
                int jj = base + __builtin_ctzll(mask);
                if (cnt == 0) i0 = jj; else if (cnt == 1) i1 = jj;
                else if (cnt == 2) i2 = jj; else i3 = jj;
                cnt++;
                mask &= (mask - 1);
            }
        }
        if (cnt >= 1) {                             // duplicate-first fill
            if (cnt <= 1) i1 = i0;
            if (cnt <= 2) i2 = i0;
            if (cnt <= 3) i3 = i0;
        }

        {   // gather: lane -> (s,c)
            int s = lane >> 4, c = lane & 15;
            int id = (s == 0) ? i0 : (s == 1) ? i1 : (s == 2) ? i2 : i3;
            float gv = 0.0f;
            if (cnt > 0) gv = pts[(size_t)id * C_ + c];
            g[wave][s][c] = gv;                     // empty query -> 0 -> h=bias
        }
        __syncthreads();                            // uniform: 2 per qi, all waves

        float* hrow = h + (size_t)m * (D_ * S_);
        #pragma unroll
        for (int r = 0; r < 2; r++) {
            int o = lane + 64 * r;
            float wc[C_];
            #pragma unroll
            for (int c = 0; c < C_; c++) wc[c] = wf[W_CONV + o * C_ + c];
            float bo = wf[W_CONVB + o];
            float a[4];
            #pragma unroll
            for (int s = 0; s < S_; s++) {
                float acc = bo;
                #pragma unroll
                for (int c = 0; c < C_; c++) acc += wc[c] * g[wave][s][c];
                a[s] = acc;
            }
            *reinterpret_cast<float4*>(hrow + o * 4) = make_float4(a[0], a[1], a[2], a[3]);
            acc_sum[r] += (a[0] + a[1]) + (a[2] + a[3]);
            acc_sq[r]  += (a[0] * a[0] + a[1] * a[1]) + (a[2] * a[2] + a[3] * a[3]);
        }
        __syncthreads();                            // g[wave] safe to overwrite
    }

    red[0][wave * 128 + lane]      = acc_sum[0];
    red[0][wave * 128 + 64 + lane] = acc_sum[1];
    red[1][wave * 128 + lane]      = acc_sq[0];
    red[1][wave * 128 + 64 + lane] = acc_sq[1];
    __syncthreads();
    if (tid < 128) {
        float s0 = (red[0][tid] + red[0][128 + tid]) + (red[0][256 + tid] + red[0][384 + tid]);
        float s1 = (red[1][tid] + red[1][128 + tid]) + (red[1][256 + tid] + red[1][384 + tid]);
        atomicAdd(&st[tid], s0);
        atomicAdd(&st[128 + tid], s1);
    }
}

__global__ void k_bn1fin(float* __restrict__ st, const float* __restrict__ wf) {
    int o = threadIdx.x;
    float mean = st[o] * (1.0f / 32768.0f);
    float var = st[128 + o] * (1.0f / 32768.0f) - mean * mean;
    float sc = wf[W_BNG + o] / sqrtf(fmaxf(var, 0.0f) + EPS_);
    st[256 + o] = sc;
    st[384 + o] = wf[W_BNB + o] - mean * sc;
}

// 512 WG x 256. Fused: bn1+max -> LDS (and feature out), 3x 128x128 FC from LDS,
// y write + branch-BN stats (LDS pre-reduce + atomics). 16 m-rows per block.
__global__ __launch_bounds__(256) void k_fc(const float* __restrict__ h,
                                            const float* __restrict__ wf,
                                            float* __restrict__ st,
                                            float* __restrict__ y,
                                            void* __restrict__ outbase,
                                            const float* __restrict__ flag) {
    int tid = threadIdx.x;
    int m0 = blockIdx.x * 16;
    __shared__ float hs[16 * 128];
    bool isf = (*flag != 0.0f);

    for (int i = tid; i < 16 * 128; i += 256) {
        int ml = i >> 7, o = i & 127;
        float4 v = *reinterpret_cast<const float4*>(h + (size_t)(m0 + ml) * 512 + o * 4);
        float sc = st[256 + o], sh = st[384 + o];
        float r = fmaxf(fmaxf(v.x * sc + sh, v.y * sc + sh),
                        fmaxf(v.z * sc + sh, v.w * sc + sh));
        hs[ml * 128 + o] = r;
        size_t idx = (size_t)OUT_FEAT + (size_t)(m0 + ml) * 128 + o;
        if (isf) ((float*)outbase)[idx] = r;
        else     ((u16*)outbase)[idx] = f2bf(r);
    }
    __syncthreads();

    int o = tid & 127, gr = tid >> 7;
    int mbase = gr * 8;
    const int woff[3] = {W_FC1, W_FC2, W_FC3};
    const int boff[3] = {W_FC1B, W_FC2B, W_FC3B};
    float acc[3][8];
    #pragma unroll
    for (int k = 0; k < 3; k++) {
        float bb = wf[boff[k] + o];
        #pragma unroll
        for (int mm = 0; mm < 8; mm++) acc[k][mm] = bb;
    }
    for (int c = 0; c < 128; c += 4) {
        float4 hv[8];
        #pragma unroll
        for (int mm = 0; mm < 8; mm++)
            hv[mm] = *reinterpret_cast<const float4*>(&hs[(mbase + mm) * 128 + c]);
        #pragma unroll
        for (int k = 0; k < 3; k++) {
            float4 w4 = *reinterpret_cast<const float4*>(wf + woff[k] + o * 128 + c);
            #pragma unroll
            for (int mm = 0; mm < 8; mm++) {
                acc[k][mm] += w4.x * hv[mm].x;
                acc[k][mm] += w4.y * hv[mm].y;
                acc[k][mm] += w4.z * hv[mm].z;
                acc[k][mm] += w4.w * hv[mm].w;
            }
        }
    }
    __syncthreads();   // hs reads done; reuse as stats scratch
    float psum[3], psq[3];
    #pragma unroll
    for (int k = 0; k < 3; k++) {
        float s = 0.0f, sq = 0.0f;
        float* yk = y + (size_t)k * M_ * 128;
        #pragma unroll
        for (int mm = 0; mm < 8; mm++) {
            float v = acc[k][mm];
            yk[(size_t)(m0 + mbase + mm) * 128 + o] = v;
            s += v; sq += v * v;
        }
        psum[k] = s; psq[k] = sq;
    }
    #pragma unroll
    for (int k = 0; k < 3; k++) {
        hs[(k * 2 + gr) * 128 + o] = psum[k];
        hs[768 + (k * 2 + gr) * 128 + o] = psq[k];
    }
    __syncthreads();
    // 384 reduce items, only 256 threads: strided loop (round-3 bug: `if (tid<384)`
    // silently skipped k=2 -> theta-branch BN normalized by poison variance).
    for (int t = tid; t < 384; t += 256) {
        int k = t >> 7, oo = t & 127;
        float s  = hs[(k * 2) * 128 + oo] + hs[(k * 2 + 1) * 128 + oo];
        float sq = hs[768 + (k * 2) * 128 + oo] + hs[768 + (k * 2 + 1) * 128 + oo];
        int base = 512 + k * 512;
        atomicAdd(&st[base + oo], s);
        atomicAdd(&st[base + 128 + oo], sq);
    }
}

__global__ void k_bnbfin(float* __restrict__ st, const float* __restrict__ wf) {
    int t = threadIdx.x;  // 0..383
    int k = t >> 7, o = t & 127;
    int base = 512 + k * 512;
    float mean = st[base + o] * (1.0f / 8192.0f);
    float var = st[base + 128 + o] * (1.0f / 8192.0f) - mean * mean;
    float sc = wf[W_BNG + o] / sqrtf(fmaxf(var, 0.0f) + EPS_);
    st[base + 256 + o] = sc;
    st[base + 384 + o] = wf[W_BNB + o] - mean * sc;
}

// 256 WG x 256 (4 waves). Each wave: 8 rows. bn+relu on y1/2/3 + head matmuls.
__global__ __launch_bounds__(256) void k_heads(const float* __restrict__ y,
                                               const float* __restrict__ st,
                                               const float* __restrict__ wf,
                                               void* __restrict__ outbase,
                                               const float* __restrict__ flag) {
    int tid = threadIdx.x;
    int wave = tid >> 6, lane = tid & 63;
    bool isf = (*flag != 0.0f);
    const float* y1 = y;
    const float* y2 = y + (size_t)M_ * D_;
    const float* y3 = y + 2 * (size_t)M_ * D_;
    for (int i = 0; i < 8; i++) {
        int m = blockIdx.x * 32 + wave * 8 + i;
        float p[7] = {0, 0, 0, 0, 0, 0, 0};
        #pragma unroll
        for (int cc = 0; cc < 2; cc++) {
            int c = lane + 64 * cc;
            float v1 = fmaxf(y1[(size_t)m * D_ + c] * st[768 + c] + st[896 + c], 0.0f);
            float v2 = fmaxf(y2[(size_t)m * D_ + c] * st[1280 + c] + st[1408 + c], 0.0f);
            float v3 = fmaxf(y3[(size_t)m * D_ + c] * st[1792 + c] + st[1920 + c], 0.0f);
            p[0] += v1 * wf[W_CE + c];
            p[1] += v1 * wf[W_CE + 128 + c];
            p[2] += v1 * wf[W_CE + 256 + c];
            p[3] += v2 * wf[W_LWH + c];
            p[4] += v2 * wf[W_LWH + 128 + c];
            p[5] += v2 * wf[W_LWH + 256 + c];
            p[6] += v3 * wf[W_TH + c];
        }
        #pragma unroll
        for (int off = 32; off > 0; off >>= 1) {
            #pragma unroll
            for (int j = 0; j < 7; j++) p[j] += __shfl_xor(p[j], off);
        }
        if (lane == 0) {
            float o0 = p[0] + wf[W_CEB + 0];
            float o1 = p[1] + wf[W_CEB + 1];
            float o2 = p[2] + wf[W_CEB + 2];
            float o3 = p[3] + wf[W_LWHB + 0];
            float o4 = p[4] + wf[W_LWHB + 1];
            float o5 = p[5] + wf[W_LWHB + 2];
            float o6 = p[6] + wf[W_THB];
            if (isf) {
                float* po = (float*)outbase;
                po[m * 7 + 0] = o0; po[m * 7 + 1] = o1; po[m * 7 + 2] = o2;
                po[m * 7 + 3] = o3; po[m * 7 + 4] = o4; po[m * 7 + 5] = o5;
                po[m * 7 + 6] = o6;
            } else {
                u16* po = (u16*)outbase;
                po[m * 7 + 0] = f2bf(o0); po[m * 7 + 1] = f2bf(o1); po[m * 7 + 2] = f2bf(o2);
                po[m * 7 + 3] = f2bf(o3); po[m * 7 + 4] = f2bf(o4); po[m * 7 + 5] = f2bf(o5);
                po[m * 7 + 6] = f2bf(o6);
            }
        }
    }
}

extern "C" void kernel_launch(void* const* d_in, const int* in_sizes, int n_in,
                              void* d_out, int out_size, void* d_ws, size_t ws_size,
                              hipStream_t stream) {
    (void)in_sizes; (void)n_in; (void)out_size; (void)ws_size;
    float* ws   = (float*)d_ws;
    float* xf   = ws + XF_OFF;
    float* wf   = ws + WF_OFF;
    float* h    = ws + H_OFF;
    float* y    = ws + Y_OFF;
    float* st   = ws + ST_OFF;
    float* flag = ws + FLAG_OFF;

    P16 ps;
    for (int i = 0; i < 16; i++) ps.p[i] = d_in[i + 1];

    hipLaunchKernelGGL(k_init,     dim3(1),    dim3(256), 0, stream, d_in[0], st, flag);
    hipLaunchKernelGGL(k_convert,  dim3(512),  dim3(256), 0, stream, d_in[0], ps, flag, xf, wf);
    hipLaunchKernelGGL(k_ballconv, dim3(1024), dim3(256), 0, stream, xf, wf, h, st);
    hipLaunchKernelGGL(k_bn1fin,   dim3(1),    dim3(128), 0, stream, st, wf);
    hipLaunchKernelGGL(k_fc,       dim3(512),  dim3(256), 0, stream, h, wf, st, y, d_out, flag);
    hipLaunchKernelGGL(k_bnbfin,   dim3(1),    dim3(384), 0, stream, st, wf);
    hipLaunchKernelGGL(k_heads,    dim3(256),  dim3(256), 0, stream, y, st, wf, d_out, flag);
}

// Round 5
// 227.582 us; speedup vs baseline: 1.3498x; 1.1314x over previous
//
#include <hip/hip_runtime.h>

#define B_   2
#define T_   5
#define N_   4096
#define C_   16
#define D_   128
#define S_   4
#define NS_  16384   // (T-1)*N
#define M_   8192    // B*N
#define EPS_ 1e-5f

// ---- ws layout (fp32 element offsets) ----
#define H_OFF   0u          // h: M*512 = 4194304
#define Y_OFF   4194304u    // y: 3*M*128 = 3145728
#define ST_OFF  7340032u    // stats: 2048 floats
// st: [0..127] sum_h, [128..255] sumsq_h; branch k: 512+k*512 (+0 sum, +128 sumsq)

#define OUT_FEAT 57344      // element offset of feature within d_out (fp32)

// 1 WG: zero the stats region.
__global__ __launch_bounds__(256) void k_init(float* __restrict__ st) {
    int tid = threadIdx.x;
    #pragma unroll
    for (int i = 0; i < 8; i++) st[tid + 256 * i] = 0.0f;
}

// 8192 blocks x 64 (1 wave = 1 query). Ball query (first-4-by-index, d2<1) with
// 512-point chunks / 8 independent loads per iteration (tail = 32 iters max),
// then gather + conv1 (16->128 over 4 samples). No atomics here.
__global__ __launch_bounds__(64) void k_ballconv(const float* __restrict__ x,
                                                 const float* __restrict__ w,
                                                 const float* __restrict__ bias,
                                                 float* __restrict__ h) {
    int m = blockIdx.x;
    int b = m >> 12, q = m & (N_ - 1);
    int lane = threadIdx.x;
    const float* xb = x + (size_t)b * (T_ * N_ * C_);
    float qx = xb[q * C_ + 0];
    float qy = xb[q * C_ + 1];
    float qz = xb[q * C_ + 2];
    float qn = (qx * qx + qy * qy) + qz * qz;
    const float* pts = xb + N_ * C_;   // x[b,1:,:,:]: 16384 rows of 16

    int i0 = 0, i1 = 0, i2 = 0, i3 = 0;
    int cnt = 0;
    for (int it = 0; it < 32 && cnt < 4; it++) {
        int base = it * 512;
        float4 pv[8];
        #pragma unroll
        for (int u = 0; u < 8; u++)   // 8 independent coalesced loads (MLP depth 8)
            pv[u] = *reinterpret_cast<const float4*>(pts + (size_t)(base + u * 64 + lane) * C_);
        unsigned long long mk[8];
        #pragma unroll
        for (int u = 0; u < 8; u++) {
            float pn = (pv[u].x * pv[u].x + pv[u].y * pv[u].y) + pv[u].z * pv[u].z;
            float dot = (qx * pv[u].x + qy * pv[u].y) + qz * pv[u].z;
            float d2 = (qn + pn) - 2.0f * dot;   // reference's algebraic form
            mk[u] = __ballot(d2 < 1.0f);
        }
        #pragma unroll
        for (int u = 0; u < 8; u++) {
            unsigned long long mask = mk[u];
            while (mask && cnt < 4) {            // wave-uniform
                int jj = base + u * 64 + __builtin_ctzll(mask);
                if (cnt == 0) i0 = jj; else if (cnt == 1) i1 = jj;
                else if (cnt == 2) i2 = jj; else i3 = jj;
                cnt++;
                mask &= (mask - 1);
            }
        }
    }
    if (cnt >= 1) {                              // duplicate-first fill
        if (cnt <= 1) i1 = i0;
        if (cnt <= 2) i2 = i0;
        if (cnt <= 3) i3 = i0;
    }

    __shared__ float g[S_][C_];
    {
        int s = lane >> 4, c = lane & 15;
        int id = (s == 0) ? i0 : (s == 1) ? i1 : (s == 2) ? i2 : i3;
        float gv = 0.0f;
        if (cnt > 0) gv = pts[(size_t)id * C_ + c];
        g[s][c] = gv;                            // empty query -> 0 -> h = bias
    }
    __syncthreads();                             // single-wave block: waitcnt only

    float* hrow = h + (size_t)m * (D_ * S_);
    #pragma unroll
    for (int r = 0; r < 2; r++) {
        int o = lane + 64 * r;
        float wc[C_];
        #pragma unroll
        for (int c = 0; c < C_; c++) wc[c] = w[o * C_ + c];
        float bo = bias[o];
        float a[4];
        #pragma unroll
        for (int s = 0; s < S_; s++) {
            float acc = bo;
            #pragma unroll
            for (int c = 0; c < C_; c++) acc += wc[c] * g[s][c];
            a[s] = acc;
        }
        *reinterpret_cast<float4*>(hrow + o * 4) = make_float4(a[0], a[1], a[2], a[3]);
    }
}

// 64 WG x 512: per-channel sum/sumsq of h over (m,s); coalesced, LDS pre-reduce.
__global__ __launch_bounds__(512) void k_bn1stats(const float* __restrict__ h,
                                                  float* __restrict__ st) {
    int t = threadIdx.x;
    float sum = 0.0f, sq = 0.0f;
    for (int m = blockIdx.x; m < M_; m += gridDim.x) {
        float v = h[(size_t)m * 512 + t];
        sum += v; sq += v * v;
    }
    __shared__ float sm[512];
    sm[t] = sum;
    __syncthreads();
    if (t < 128) atomicAdd(&st[t], sm[4 * t] + sm[4 * t + 1] + sm[4 * t + 2] + sm[4 * t + 3]);
    __syncthreads();
    sm[t] = sq;
    __syncthreads();
    if (t < 128) atomicAdd(&st[128 + t], sm[4 * t] + sm[4 * t + 1] + sm[4 * t + 2] + sm[4 * t + 3]);
}

// 512 WG x 256. Inline bn1 finalize, bn1+max -> LDS (+ feature out), 3x 128x128
// FC from LDS, y write + branch-BN stats (LDS pre-reduce + atomics). 16 rows/blk.
__global__ __launch_bounds__(256) void k_fc(const float* __restrict__ h,
                                            float* __restrict__ st,
                                            const float* __restrict__ w1, const float* __restrict__ b1,
                                            const float* __restrict__ w2, const float* __restrict__ b2,
                                            const float* __restrict__ w3, const float* __restrict__ b3,
                                            const float* __restrict__ bng, const float* __restrict__ bnb,
                                            float* __restrict__ y,
                                            float* __restrict__ out) {
    int tid = threadIdx.x;
    int m0 = blockIdx.x * 16;
    __shared__ float hs[16 * 128];
    __shared__ float scsh[256];    // [0..127] scale1, [128..255] shift1

    if (tid < 128) {               // inline bn1 finalize (redundant per block, cheap)
        float mean = st[tid] * (1.0f / 32768.0f);
        float var = st[128 + tid] * (1.0f / 32768.0f) - mean * mean;
        float sc = bng[tid] / sqrtf(fmaxf(var, 0.0f) + EPS_);
        scsh[tid] = sc;
        scsh[128 + tid] = bnb[tid] - mean * sc;
    }
    __syncthreads();

    for (int i = tid; i < 16 * 128; i += 256) {
        int ml = i >> 7, o = i & 127;
        float4 v = *reinterpret_cast<const float4*>(h + (size_t)(m0 + ml) * 512 + o * 4);
        float sc = scsh[o], sh = scsh[128 + o];
        float r = fmaxf(fmaxf(v.x * sc + sh, v.y * sc + sh),
                        fmaxf(v.z * sc + sh, v.w * sc + sh));
        hs[ml * 128 + o] = r;
        out[(size_t)OUT_FEAT + (size_t)(m0 + ml) * 128 + o] = r;
    }
    __syncthreads();

    int o = tid & 127, gr = tid >> 7;
    int mbase = gr * 8;
    const float* wks[3] = { w1, w2, w3 };
    const float* bks[3] = { b1, b2, b3 };
    float acc[3][8];
    #pragma unroll
    for (int k = 0; k < 3; k++) {
        float bb = bks[k][o];
        #pragma unroll
        for (int mm = 0; mm < 8; mm++) acc[k][mm] = bb;
    }
    for (int c = 0; c < 128; c += 4) {
        float4 hv[8];
        #pragma unroll
        for (int mm = 0; mm < 8; mm++)
            hv[mm] = *reinterpret_cast<const float4*>(&hs[(mbase + mm) * 128 + c]);
        #pragma unroll
        for (int k = 0; k < 3; k++) {
            float4 w4 = *reinterpret_cast<const float4*>(wks[k] + o * 128 + c);
            #pragma unroll
            for (int mm = 0; mm < 8; mm++) {
                acc[k][mm] += w4.x * hv[mm].x;
                acc[k][mm] += w4.y * hv[mm].y;
                acc[k][mm] += w4.z * hv[mm].z;
                acc[k][mm] += w4.w * hv[mm].w;
            }
        }
    }
    __syncthreads();   // hs reads done; reuse as stats scratch
    float psum[3], psq[3];
    #pragma unroll
    for (int k = 0; k < 3; k++) {
        float s = 0.0f, sq = 0.0f;
        float* yk = y + (size_t)k * M_ * 128;
        #pragma unroll
        for (int mm = 0; mm < 8; mm++) {
            float v = acc[k][mm];
            yk[(size_t)(m0 + mbase + mm) * 128 + o] = v;
            s += v; sq += v * v;
        }
        psum[k] = s; psq[k] = sq;
    }
    #pragma unroll
    for (int k = 0; k < 3; k++) {
        hs[(k * 2 + gr) * 128 + o] = psum[k];
        hs[768 + (k * 2 + gr) * 128 + o] = psq[k];
    }
    __syncthreads();
    // 384 items, 256 threads: strided (round-3 bug was `if (tid<384)`)
    for (int t = tid; t < 384; t += 256) {
        int k = t >> 7, oo = t & 127;
        float s  = hs[(k * 2) * 128 + oo] + hs[(k * 2 + 1) * 128 + oo];
        float sq = hs[768 + (k * 2) * 128 + oo] + hs[768 + (k * 2 + 1) * 128 + oo];
        int base = 512 + k * 512;
        atomicAdd(&st[base + oo], s);
        atomicAdd(&st[base + 128 + oo], sq);
    }
}

// 256 WG x 256 (4 waves, 8 rows/wave). Inline branch-BN finalize, bn+relu,
// head matmuls, 7 fp32 outputs per row.
__global__ __launch_bounds__(256) void k_heads(const float* __restrict__ y,
                                               const float* __restrict__ st,
                                               const float* __restrict__ wce, const float* __restrict__ bce,
                                               const float* __restrict__ wlwh, const float* __restrict__ blwh,
                                               const float* __restrict__ wth, const float* __restrict__ bth,
                                               const float* __restrict__ bng, const float* __restrict__ bnb,
                                               float* __restrict__ out) {
    int tid = threadIdx.x;
    __shared__ float bsc[768];     // k*256 + [0..127]=scale, [128..255]=shift
    for (int t = tid; t < 384; t += 256) {
        int k = t >> 7, o = t & 127;
        int base = 512 + k * 512;
        float mean = st[base + o] * (1.0f / 8192.0f);
        float var = st[base + 128 + o] * (1.0f / 8192.0f) - mean * mean;
        float sc = bng[o] / sqrtf(fmaxf(var, 0.0f) + EPS_);
        bsc[k * 256 + o] = sc;
        bsc[k * 256 + 128 + o] = bnb[o] - mean * sc;
    }
    __syncthreads();

    int wave = tid >> 6, lane = tid & 63;
    const float* y1 = y;
    const float* y2 = y + (size_t)M_ * D_;
    const float* y3 = y + 2 * (size_t)M_ * D_;
    for (int i = 0; i < 8; i++) {
        int m = blockIdx.x * 32 + wave * 8 + i;
        float p[7] = {0, 0, 0, 0, 0, 0, 0};
        #pragma unroll
        for (int cc = 0; cc < 2; cc++) {
            int c = lane + 64 * cc;
            float v1 = fmaxf(y1[(size_t)m * D_ + c] * bsc[c] + bsc[128 + c], 0.0f);
            float v2 = fmaxf(y2[(size_t)m * D_ + c] * bsc[256 + c] + bsc[384 + c], 0.0f);
            float v3 = fmaxf(y3[(size_t)m * D_ + c] * bsc[512 + c] + bsc[640 + c], 0.0f);
            p[0] += v1 * wce[c];
            p[1] += v1 * wce[128 + c];
            p[2] += v1 * wce[256 + c];
            p[3] += v2 * wlwh[c];
            p[4] += v2 * wlwh[128 + c];
            p[5] += v2 * wlwh[256 + c];
            p[6] += v3 * wth[c];
        }
        #pragma unroll
        for (int off = 32; off > 0; off >>= 1) {
            #pragma unroll
            for (int j = 0; j < 7; j++) p[j] += __shfl_xor(p[j], off);
        }
        if (lane == 0) {
            out[m * 7 + 0] = p[0] + bce[0];
            out[m * 7 + 1] = p[1] + bce[1];
            out[m * 7 + 2] = p[2] + bce[2];
            out[m * 7 + 3] = p[3] + blwh[0];
            out[m * 7 + 4] = p[4] + blwh[1];
            out[m * 7 + 5] = p[5] + blwh[2];
            out[m * 7 + 6] = p[6] + bth[0];
        }
    }
}

extern "C" void kernel_launch(void* const* d_in, const int* in_sizes, int n_in,
                              void* d_out, int out_size, void* d_ws, size_t ws_size,
                              hipStream_t stream) {
    (void)in_sizes; (void)n_in; (void)out_size; (void)ws_size;
    const float* x        = (const float*)d_in[0];
    const float* conv1_w  = (const float*)d_in[1];
    const float* conv1_b  = (const float*)d_in[2];
    const float* bn_g     = (const float*)d_in[3];
    const float* bn_b     = (const float*)d_in[4];
    const float* fc1_w    = (const float*)d_in[5];
    const float* fc1_b    = (const float*)d_in[6];
    const float* fc_ce_w  = (const float*)d_in[7];
    const float* fc_ce_b  = (const float*)d_in[8];
    const float* fc2_w    = (const float*)d_in[9];
    const float* fc2_b    = (const float*)d_in[10];
    const float* fc_lwh_w = (const float*)d_in[11];
    const float* fc_lwh_b = (const float*)d_in[12];
    const float* fc3_w    = (const float*)d_in[13];
    const float* fc3_b    = (const float*)d_in[14];
    const float* fc_th_w  = (const float*)d_in[15];
    const float* fc_th_b  = (const float*)d_in[16];

    float* ws = (float*)d_ws;
    float* h  = ws + H_OFF;
    float* y  = ws + Y_OFF;
    float* st = ws + ST_OFF;
    float* out = (float*)d_out;

    hipLaunchKernelGGL(k_init,     dim3(1),    dim3(256), 0, stream, st);
    hipLaunchKernelGGL(k_ballconv, dim3(M_),   dim3(64),  0, stream, x, conv1_w, conv1_b, h);
    hipLaunchKernelGGL(k_bn1stats, dim3(64),   dim3(512), 0, stream, h, st);
    hipLaunchKernelGGL(k_fc,       dim3(512),  dim3(256), 0, stream, h, st,
                       fc1_w, fc1_b, fc2_w, fc2_b, fc3_w, fc3_b, bn_g, bn_b, y, out);
    hipLaunchKernelGGL(k_heads,    dim3(256),  dim3(256), 0, stream, y, st,
                       fc_ce_w, fc_ce_b, fc_lwh_w, fc_lwh_b, fc_th_w, fc_th_b, bn_g, bn_b, out);
}

// Round 6
// 198.698 us; speedup vs baseline: 1.5460x; 1.1454x over previous
//
#include <hip/hip_runtime.h>

#define B_   2
#define T_   5
#define N_   4096
#define C_   16
#define D_   128
#define S_   4
#define NS_  16384   // (T-1)*N
#define M_   8192    // B*N
#define EPS_ 1e-5f

// ---- ws layout (fp32 element offsets) ----
#define H_OFF   0u          // h: M*512 = 4194304
#define Y_OFF   4194304u    // y: 3*M*128 = 3145728
#define ST_OFF  7340032u    // stats: 2048 floats
#define WP_OFF  7342080u    // packed transposed FC weights: 3*16384 floats
// st: [0..127] sum_h, [128..255] sumsq_h; branch k: 512+k*512 (+0 sum, +128 sumsq)

#define OUT_FEAT 57344      // element offset of feature within d_out (fp32)

// 528 WGs x 256. WGs [0,512): 4 independent waves, 4 queries each — ball query
// (first-4-by-index, d2<1) in 512-point chunks (8 parallel loads), gather via
// __shfl, conv1 with register-hoisted weights. No barriers, no LDS.
// WGs [512,528): pack FC weights into transposed float4 layout + zero stats.
__global__ __launch_bounds__(256) void k_ballconv(const float* __restrict__ x,
                                                  const float* __restrict__ w,
                                                  const float* __restrict__ bias,
                                                  const float* __restrict__ fw1,
                                                  const float* __restrict__ fw2,
                                                  const float* __restrict__ fw3,
                                                  float* __restrict__ h,
                                                  float* __restrict__ st,
                                                  float4* __restrict__ wp) {
    int tid = threadIdx.x;
    if (blockIdx.x >= 512) {                    // pack + zero WGs
        int pb = blockIdx.x - 512;              // 0..15
        if (pb == 0) {
            #pragma unroll
            for (int i = 0; i < 8; i++) st[tid + 256 * i] = 0.0f;
        }
        int idx = pb * 256 + tid;               // 0..4095 float4s per FC
        int o = idx >> 5, c4 = idx & 31;        // read-coalesced over c4
        const float* fws[3] = { fw1, fw2, fw3 };
        #pragma unroll
        for (int k = 0; k < 3; k++)
            wp[k * 4096 + c4 * 128 + o] = *(const float4*)(fws[k] + o * 128 + c4 * 4);
        return;
    }

    int wid = tid >> 6, lane = tid & 63;
    float wc0[16], wc1[16];                     // conv1 rows lane, lane+64
    #pragma unroll
    for (int j = 0; j < 4; j++) {
        float4 a = *(const float4*)(w + lane * 16 + j * 4);
        float4 b2 = *(const float4*)(w + (lane + 64) * 16 + j * 4);
        wc0[j*4+0] = a.x;  wc0[j*4+1] = a.y;  wc0[j*4+2] = a.z;  wc0[j*4+3] = a.w;
        wc1[j*4+0] = b2.x; wc1[j*4+1] = b2.y; wc1[j*4+2] = b2.z; wc1[j*4+3] = b2.w;
    }
    float bo0 = bias[lane], bo1 = bias[lane + 64];

    for (int qi = 0; qi < 4; qi++) {
        int m = (blockIdx.x * 4 + wid) * 4 + qi;
        int b = m >> 12, q = m & (N_ - 1);
        const float* xb = x + (size_t)b * (T_ * N_ * C_);
        const float* pts = xb + N_ * C_;        // 16384 rows of 16
        float qx = xb[q * 16 + 0];
        float qy = xb[q * 16 + 1];
        float qz = xb[q * 16 + 2];
        float qn = (qx * qx + qy * qy) + qz * qz;

        int i0 = 0, i1 = 0, i2 = 0, i3 = 0, cnt = 0;
        for (int it = 0; it < 32 && cnt < 4; it++) {
            int base = it * 512;
            float4 pv[8];
            #pragma unroll
            for (int u = 0; u < 8; u++)         // 8 independent coalesced loads
                pv[u] = *(const float4*)(pts + (size_t)(base + u * 64 + lane) * 16);
            unsigned long long mk[8];
            #pragma unroll
            for (int u = 0; u < 8; u++) {
                float pn = (pv[u].x * pv[u].x + pv[u].y * pv[u].y) + pv[u].z * pv[u].z;
                float dot = (qx * pv[u].x + qy * pv[u].y) + qz * pv[u].z;
                mk[u] = __ballot((qn + pn) - 2.0f * dot < 1.0f);  // reference form
            }
            #pragma unroll
            for (int u = 0; u < 8; u++) {
                unsigned long long mask = mk[u];
                while (mask && cnt < 4) {       // wave-uniform scalar loop
                    int jj = base + u * 64 + __builtin_ctzll(mask);
                    if (cnt == 0) i0 = jj; else if (cnt == 1) i1 = jj;
                    else if (cnt == 2) i2 = jj; else i3 = jj;
                    cnt++;
                    mask &= (mask - 1);
                }
            }
        }
        if (cnt >= 1) {                         // duplicate-first fill
            if (cnt <= 1) i1 = i0;
            if (cnt <= 2) i2 = i0;
            if (cnt <= 3) i3 = i0;
        }

        // gather: lane l holds g[s=l>>4][c=l&15]; broadcast via shuffle
        int sidx = lane >> 4, cidx = lane & 15;
        int gid = (sidx == 0) ? i0 : (sidx == 1) ? i1 : (sidx == 2) ? i2 : i3;
        float gv = (cnt > 0) ? pts[(size_t)gid * 16 + cidx] : 0.0f;

        float a0[4], a1[4];
        #pragma unroll
        for (int s = 0; s < 4; s++) { a0[s] = bo0; a1[s] = bo1; }
        #pragma unroll
        for (int s = 0; s < 4; s++) {
            #pragma unroll
            for (int c = 0; c < 16; c++) {
                float g = __shfl(gv, s * 16 + c);
                a0[s] += wc0[c] * g;
                a1[s] += wc1[c] * g;
            }
        }
        float* hrow = h + (size_t)m * 512;
        *(float4*)(hrow + lane * 4)       = make_float4(a0[0], a0[1], a0[2], a0[3]);
        *(float4*)(hrow + 256 + lane * 4) = make_float4(a1[0], a1[1], a1[2], a1[3]);
    }
}

// 256 WG x 512: per-channel sum/sumsq of h over (m,s); coalesced, 4-way ILP.
__global__ __launch_bounds__(512) void k_bn1stats(const float* __restrict__ h,
                                                  float* __restrict__ st) {
    int t = threadIdx.x;
    float sum = 0.0f, sq = 0.0f;
    for (int m0 = blockIdx.x * 4; m0 < M_; m0 += 1024) {
        #pragma unroll
        for (int j = 0; j < 4; j++) {           // 4 independent loads in flight
            float v = h[(size_t)(m0 + j) * 512 + t];
            sum += v; sq += v * v;
        }
    }
    __shared__ float sm[512];
    sm[t] = sum;
    __syncthreads();
    if (t < 128) atomicAdd(&st[t], sm[4 * t] + sm[4 * t + 1] + sm[4 * t + 2] + sm[4 * t + 3]);
    __syncthreads();
    sm[t] = sq;
    __syncthreads();
    if (t < 128) atomicAdd(&st[128 + t], sm[4 * t] + sm[4 * t + 1] + sm[4 * t + 2] + sm[4 * t + 3]);
}

// 256 WG x 256, m-tile 32. Inline bn1 finalize, bn1+max -> LDS (+ feature out),
// 3x 128x128 FC with coalesced packed-transpose weights + LDS-broadcast h,
// y write + branch-BN stats (LDS pre-reduce + atomics).
__global__ __launch_bounds__(256) void k_fc(const float* __restrict__ h,
                                            float* __restrict__ st,
                                            const float4* __restrict__ wp,
                                            const float* __restrict__ b1,
                                            const float* __restrict__ b2,
                                            const float* __restrict__ b3,
                                            const float* __restrict__ bng,
                                            const float* __restrict__ bnb,
                                            float* __restrict__ y,
                                            float* __restrict__ out) {
    int tid = threadIdx.x;
    int m0 = blockIdx.x * 32;
    __shared__ float hs[32 * 128];
    __shared__ float scsh[256];                 // [0..127] scale1, [128..255] shift1

    if (tid < 128) {                            // inline bn1 finalize
        float mean = st[tid] * (1.0f / 32768.0f);
        float var = st[128 + tid] * (1.0f / 32768.0f) - mean * mean;
        float sc = bng[tid] / sqrtf(fmaxf(var, 0.0f) + EPS_);
        scsh[tid] = sc;
        scsh[128 + tid] = bnb[tid] - mean * sc;
    }
    __syncthreads();

    for (int i = tid; i < 32 * 128; i += 256) {
        int ml = i >> 7, o = i & 127;
        float4 v = *(const float4*)(h + (size_t)(m0 + ml) * 512 + o * 4);
        float sc = scsh[o], sh = scsh[128 + o];
        float r = fmaxf(fmaxf(v.x * sc + sh, v.y * sc + sh),
                        fmaxf(v.z * sc + sh, v.w * sc + sh));
        hs[ml * 128 + o] = r;
        out[(size_t)OUT_FEAT + (size_t)(m0 + ml) * 128 + o] = r;
    }
    __syncthreads();

    int o = tid & 127, gr = tid >> 7;
    int mbase = gr * 16;
    float acc[3][16];
    {
        float bb0 = b1[o], bb1 = b2[o], bb2 = b3[o];
        #pragma unroll
        for (int mm = 0; mm < 16; mm++) {
            acc[0][mm] = bb0; acc[1][mm] = bb1; acc[2][mm] = bb2;
        }
    }
    for (int c4 = 0; c4 < 32; c4++) {
        float4 w1v = wp[c4 * 128 + o];          // coalesced 16B/lane
        float4 w2v = wp[4096 + c4 * 128 + o];
        float4 w3v = wp[8192 + c4 * 128 + o];
        const float* hp = &hs[mbase * 128 + c4 * 4];
        #pragma unroll
        for (int mm = 0; mm < 16; mm++) {
            float4 hv = *(const float4*)(hp + mm * 128);   // wave-uniform broadcast
            acc[0][mm] += w1v.x * hv.x; acc[0][mm] += w1v.y * hv.y;
            acc[0][mm] += w1v.z * hv.z; acc[0][mm] += w1v.w * hv.w;
            acc[1][mm] += w2v.x * hv.x; acc[1][mm] += w2v.y * hv.y;
            acc[1][mm] += w2v.z * hv.z; acc[1][mm] += w2v.w * hv.w;
            acc[2][mm] += w3v.x * hv.x; acc[2][mm] += w3v.y * hv.y;
            acc[2][mm] += w3v.z * hv.z; acc[2][mm] += w3v.w * hv.w;
        }
    }
    __syncthreads();                            // all hs reads done; reuse as scratch
    float psum[3], psq[3];
    #pragma unroll
    for (int k = 0; k < 3; k++) {
        float s = 0.0f, sq = 0.0f;
        float* yk = y + (size_t)k * M_ * 128;
        #pragma unroll
        for (int mm = 0; mm < 16; mm++) {
            float v = acc[k][mm];
            yk[(size_t)(m0 + mbase + mm) * 128 + o] = v;
            s += v; sq += v * v;
        }
        psum[k] = s; psq[k] = sq;
    }
    #pragma unroll
    for (int k = 0; k < 3; k++) {
        hs[(k * 2 + gr) * 128 + o] = psum[k];
        hs[768 + (k * 2 + gr) * 128 + o] = psq[k];
    }
    __syncthreads();
    for (int t = tid; t < 384; t += 256) {      // strided: 384 items, 256 threads
        int k = t >> 7, oo = t & 127;
        float s  = hs[(k * 2) * 128 + oo] + hs[(k * 2 + 1) * 128 + oo];
        float sq = hs[768 + (k * 2) * 128 + oo] + hs[768 + (k * 2 + 1) * 128 + oo];
        int base = 512 + k * 512;
        atomicAdd(&st[base + oo], s);
        atomicAdd(&st[base + 128 + oo], sq);
    }
}

// 256 WG x 256 (4 waves, 8 rows/wave). Inline branch-BN finalize, bn+relu,
// head matmuls, 7 fp32 outputs per row.
__global__ __launch_bounds__(256) void k_heads(const float* __restrict__ y,
                                               const float* __restrict__ st,
                                               const float* __restrict__ wce, const float* __restrict__ bce,
                                               const float* __restrict__ wlwh, const float* __restrict__ blwh,
                                               const float* __restrict__ wth, const float* __restrict__ bth,
                                               const float* __restrict__ bng, const float* __restrict__ bnb,
                                               float* __restrict__ out) {
    int tid = threadIdx.x;
    __shared__ float bsc[768];                  // k*256 + [0..127]=scale, [128..255]=shift
    for (int t = tid; t < 384; t += 256) {
        int k = t >> 7, o = t & 127;
        int base = 512 + k * 512;
        float mean = st[base + o] * (1.0f / 8192.0f);
        float var = st[base + 128 + o] * (1.0f / 8192.0f) - mean * mean;
        float sc = bng[o] / sqrtf(fmaxf(var, 0.0f) + EPS_);
        bsc[k * 256 + o] = sc;
        bsc[k * 256 + 128 + o] = bnb[o] - mean * sc;
    }
    __syncthreads();

    int wave = tid >> 6, lane = tid & 63;
    const float* y1 = y;
    const float* y2 = y + (size_t)M_ * D_;
    const float* y3 = y + 2 * (size_t)M_ * D_;
    #pragma unroll 2
    for (int i = 0; i < 8; i++) {
        int m = blockIdx.x * 32 + wave * 8 + i;
        float p[7] = {0, 0, 0, 0, 0, 0, 0};
        #pragma unroll
        for (int cc = 0; cc < 2; cc++) {
            int c = lane + 64 * cc;
            float v1 = fmaxf(y1[(size_t)m * D_ + c] * bsc[c] + bsc[128 + c], 0.0f);
            float v2 = fmaxf(y2[(size_t)m * D_ + c] * bsc[256 + c] + bsc[384 + c], 0.0f);
            float v3 = fmaxf(y3[(size_t)m * D_ + c] * bsc[512 + c] + bsc[640 + c], 0.0f);
            p[0] += v1 * wce[c];
            p[1] += v1 * wce[128 + c];
            p[2] += v1 * wce[256 + c];
            p[3] += v2 * wlwh[c];
            p[4] += v2 * wlwh[128 + c];
            p[5] += v2 * wlwh[256 + c];
            p[6] += v3 * wth[c];
        }
        #pragma unroll
        for (int off = 32; off > 0; off >>= 1) {
            #pragma unroll
            for (int j = 0; j < 7; j++) p[j] += __shfl_xor(p[j], off);
        }
        if (lane == 0) {
            out[m * 7 + 0] = p[0] + bce[0];
            out[m * 7 + 1] = p[1] + bce[1];
            out[m * 7 + 2] = p[2] + bce[2];
            out[m * 7 + 3] = p[3] + blwh[0];
            out[m * 7 + 4] = p[4] + blwh[1];
            out[m * 7 + 5] = p[5] + blwh[2];
            out[m * 7 + 6] = p[6] + bth[0];
        }
    }
}

extern "C" void kernel_launch(void* const* d_in, const int* in_sizes, int n_in,
                              void* d_out, int out_size, void* d_ws, size_t ws_size,
                              hipStream_t stream) {
    (void)in_sizes; (void)n_in; (void)out_size; (void)ws_size;
    const float* x        = (const float*)d_in[0];
    const float* conv1_w  = (const float*)d_in[1];
    const float* conv1_b  = (const float*)d_in[2];
    const float* bn_g     = (const float*)d_in[3];
    const float* bn_b     = (const float*)d_in[4];
    const float* fc1_w    = (const float*)d_in[5];
    const float* fc1_b    = (const float*)d_in[6];
    const float* fc_ce_w  = (const float*)d_in[7];
    const float* fc_ce_b  = (const float*)d_in[8];
    const float* fc2_w    = (const float*)d_in[9];
    const float* fc2_b    = (const float*)d_in[10];
    const float* fc_lwh_w = (const float*)d_in[11];
    const float* fc_lwh_b = (const float*)d_in[12];
    const float* fc3_w    = (const float*)d_in[13];
    const float* fc3_b    = (const float*)d_in[14];
    const float* fc_th_w  = (const float*)d_in[15];
    const float* fc_th_b  = (const float*)d_in[16];

    float* ws = (float*)d_ws;
    float* h  = ws + H_OFF;
    float* y  = ws + Y_OFF;
    float* st = ws + ST_OFF;
    float4* wp = (float4*)(ws + WP_OFF);
    float* out = (float*)d_out;

    hipLaunchKernelGGL(k_ballconv, dim3(528), dim3(256), 0, stream,
                       x, conv1_w, conv1_b, fc1_w, fc2_w, fc3_w, h, st, wp);
    hipLaunchKernelGGL(k_bn1stats, dim3(256), dim3(512), 0, stream, h, st);
    hipLaunchKernelGGL(k_fc,       dim3(256), dim3(256), 0, stream, h, st, wp,
                       fc1_b, fc2_b, fc3_b, bn_g, bn_b, y, out);
    hipLaunchKernelGGL(k_heads,    dim3(256), dim3(256), 0, stream, y, st,
                       fc_ce_w, fc_ce_b, fc_lwh_w, fc_lwh_b, fc_th_w, fc_th_b, bn_g, bn_b, out);
}

// Round 7
// 190.364 us; speedup vs baseline: 1.6137x; 1.0438x over previous
//
#include <hip/hip_runtime.h>

#define B_   2
#define T_   5
#define N_   4096
#define C_   16
#define D_   128
#define S_   4
#define NS_  16384   // (T-1)*N
#define M_   8192    // B*N
#define EPS_ 1e-5f

// ---- ws layout (fp32 element offsets) ----
#define H_OFF   0u          // h: M*512 = 4194304
#define Y_OFF   4194304u    // y: 3*M*128 = 3145728
#define ST_OFF  7340032u    // stats: 2048 floats
#define WP_OFF  7342080u    // packed transposed FC weights: 3*16384 floats
#define PK_OFF  7391232u    // SoA scan data: 2*16384 float4 = 131072 floats
// st: [0..127] sum_h, [128..255] sumsq_h; branch k: 512+k*512 (+0 sum, +128 sumsq)

#define OUT_FEAT 57344      // element offset of feature within d_out (fp32)

// 144 WGs x 256. WGs [0,128): build pk4[b][j] = (px,py,pz,|p|^2) — SoA scan pack.
// WGs [128,144): pack FC weights into transposed float4 layout; WG 128 zeros st.
__global__ __launch_bounds__(256) void k_prep(const float* __restrict__ x,
                                              const float* __restrict__ fw1,
                                              const float* __restrict__ fw2,
                                              const float* __restrict__ fw3,
                                              float* __restrict__ st,
                                              float4* __restrict__ wp,
                                              float4* __restrict__ pk4) {
    int tid = threadIdx.x;
    if (blockIdx.x < 128) {
        int row = blockIdx.x * 256 + tid;       // 0..32767
        int b = row >> 14, j = row & 16383;
        const float* p = x + (size_t)b * (T_ * N_ * C_) + N_ * C_ + (size_t)j * 16;
        float4 v = *(const float4*)p;
        float pn = (v.x * v.x + v.y * v.y) + v.z * v.z;   // same expr as scan had
        pk4[row] = make_float4(v.x, v.y, v.z, pn);
        return;
    }
    int pb = blockIdx.x - 128;                  // 0..15
    if (pb == 0) {
        #pragma unroll
        for (int i = 0; i < 8; i++) st[tid + 256 * i] = 0.0f;
    }
    int idx = pb * 256 + tid;                   // 0..4095 float4s per FC
    int o = idx >> 5, c4 = idx & 31;
    const float* fws[3] = { fw1, fw2, fw3 };
    #pragma unroll
    for (int k = 0; k < 3; k++)
        wp[k * 4096 + c4 * 128 + o] = *(const float4*)(fws[k] + o * 128 + c4 * 4);
}

// 512 WGs x 256: 4 independent waves, 4 queries each. Ball query scans the SoA
// pk4 (16B/lane coalesced, 8 loads per 512-pt chunk); gathered rows use
// wave-uniform broadcast loads; conv1 with register-hoisted weights. No barriers.
__global__ __launch_bounds__(256) void k_ballconv(const float* __restrict__ x,
                                                  const float* __restrict__ w,
                                                  const float* __restrict__ bias,
                                                  const float4* __restrict__ pk4,
                                                  float* __restrict__ h) {
    int tid = threadIdx.x;
    int wid = tid >> 6, lane = tid & 63;
    float wc0[16], wc1[16];                     // conv1 rows lane, lane+64
    #pragma unroll
    for (int j = 0; j < 4; j++) {
        float4 a = *(const float4*)(w + lane * 16 + j * 4);
        float4 b2 = *(const float4*)(w + (lane + 64) * 16 + j * 4);
        wc0[j*4+0] = a.x;  wc0[j*4+1] = a.y;  wc0[j*4+2] = a.z;  wc0[j*4+3] = a.w;
        wc1[j*4+0] = b2.x; wc1[j*4+1] = b2.y; wc1[j*4+2] = b2.z; wc1[j*4+3] = b2.w;
    }
    float bo0 = bias[lane], bo1 = bias[lane + 64];

    for (int qi = 0; qi < 4; qi++) {
        int m = (blockIdx.x * 4 + wid) * 4 + qi;
        int b = m >> 12, q = m & (N_ - 1);
        const float* xb = x + (size_t)b * (T_ * N_ * C_);
        const float* pts = xb + N_ * C_;        // 16384 rows of 16
        const float4* pk = pk4 + b * 16384;
        float qx = xb[q * 16 + 0];
        float qy = xb[q * 16 + 1];
        float qz = xb[q * 16 + 2];
        float qn = (qx * qx + qy * qy) + qz * qz;

        int ids[4] = {0, 0, 0, 0};
        int cnt = 0;
        for (int it = 0; it < 32 && cnt < 4; it++) {
            int base = it * 512;
            float4 pv[8];
            #pragma unroll
            for (int u = 0; u < 8; u++)         // 16B/lane contiguous: 4 lines/load
                pv[u] = pk[base + u * 64 + lane];
            unsigned long long mk[8];
            #pragma unroll
            for (int u = 0; u < 8; u++) {
                float dot = (qx * pv[u].x + qy * pv[u].y) + qz * pv[u].z;
                mk[u] = __ballot((qn + pv[u].w) - 2.0f * dot < 1.0f);  // ref form
            }
            #pragma unroll
            for (int u = 0; u < 8; u++) {
                unsigned long long mask = mk[u];
                while (mask && cnt < 4) {       // wave-uniform scalar loop
                    ids[cnt] = base + u * 64 + __builtin_ctzll(mask);
                    cnt++;
                    mask &= (mask - 1);
                }
            }
        }
        if (cnt >= 1) {                         // duplicate-first fill
            #pragma unroll
            for (int s = 1; s < 4; s++) if (cnt <= s) ids[s] = ids[0];
        }

        float a0[4], a1[4];
        #pragma unroll
        for (int s = 0; s < 4; s++) {           // wave-uniform row addresses:
            const float* rp = pts + (size_t)ids[s] * 16;   // broadcast loads
            float4 r0 = *(const float4*)(rp);
            float4 r1 = *(const float4*)(rp + 4);
            float4 r2 = *(const float4*)(rp + 8);
            float4 r3 = *(const float4*)(rp + 12);
            float s0 = bo0, s1 = bo1;
            s0 += wc0[0] * r0.x;  s0 += wc0[1] * r0.y;  s0 += wc0[2] * r0.z;  s0 += wc0[3] * r0.w;
            s0 += wc0[4] * r1.x;  s0 += wc0[5] * r1.y;  s0 += wc0[6] * r1.z;  s0 += wc0[7] * r1.w;
            s0 += wc0[8] * r2.x;  s0 += wc0[9] * r2.y;  s0 += wc0[10] * r2.z; s0 += wc0[11] * r2.w;
            s0 += wc0[12] * r3.x; s0 += wc0[13] * r3.y; s0 += wc0[14] * r3.z; s0 += wc0[15] * r3.w;
            s1 += wc1[0] * r0.x;  s1 += wc1[1] * r0.y;  s1 += wc1[2] * r0.z;  s1 += wc1[3] * r0.w;
            s1 += wc1[4] * r1.x;  s1 += wc1[5] * r1.y;  s1 += wc1[6] * r1.z;  s1 += wc1[7] * r1.w;
            s1 += wc1[8] * r2.x;  s1 += wc1[9] * r2.y;  s1 += wc1[10] * r2.z; s1 += wc1[11] * r2.w;
            s1 += wc1[12] * r3.x; s1 += wc1[13] * r3.y; s1 += wc1[14] * r3.z; s1 += wc1[15] * r3.w;
            a0[s] = s0; a1[s] = s1;
        }
        if (cnt == 0) {                         // empty query: grouped = 0 -> bias
            #pragma unroll
            for (int s = 0; s < 4; s++) { a0[s] = bo0; a1[s] = bo1; }
        }
        float* hrow = h + (size_t)m * 512;
        *(float4*)(hrow + lane * 4)       = make_float4(a0[0], a0[1], a0[2], a0[3]);
        *(float4*)(hrow + 256 + lane * 4) = make_float4(a1[0], a1[1], a1[2], a1[3]);
    }
}

// 256 WG x 512: per-channel sum/sumsq of h over (m,s); coalesced, 4-way ILP.
__global__ __launch_bounds__(512) void k_bn1stats(const float* __restrict__ h,
                                                  float* __restrict__ st) {
    int t = threadIdx.x;
    float sum = 0.0f, sq = 0.0f;
    for (int m0 = blockIdx.x * 4; m0 < M_; m0 += 1024) {
        #pragma unroll
        for (int j = 0; j < 4; j++) {
            float v = h[(size_t)(m0 + j) * 512 + t];
            sum += v; sq += v * v;
        }
    }
    __shared__ float sm[512];
    sm[t] = sum;
    __syncthreads();
    if (t < 128) atomicAdd(&st[t], sm[4 * t] + sm[4 * t + 1] + sm[4 * t + 2] + sm[4 * t + 3]);
    __syncthreads();
    sm[t] = sq;
    __syncthreads();
    if (t < 128) atomicAdd(&st[128 + t], sm[4 * t] + sm[4 * t + 1] + sm[4 * t + 2] + sm[4 * t + 3]);
}

// 256 WG x 256, m-tile 32. Inline bn1 finalize, bn1+max -> LDS (+ feature out),
// 3x 128x128 FC with coalesced packed-transpose weights + LDS-broadcast h,
// y write + branch-BN stats (LDS pre-reduce + atomics).
__global__ __launch_bounds__(256) void k_fc(const float* __restrict__ h,
                                            float* __restrict__ st,
                                            const float4* __restrict__ wp,
                                            const float* __restrict__ b1,
                                            const float* __restrict__ b2,
                                            const float* __restrict__ b3,
                                            const float* __restrict__ bng,
                                            const float* __restrict__ bnb,
                                            float* __restrict__ y,
                                            float* __restrict__ out) {
    int tid = threadIdx.x;
    int m0 = blockIdx.x * 32;
    __shared__ float hs[32 * 128];
    __shared__ float scsh[256];                 // [0..127] scale1, [128..255] shift1

    if (tid < 128) {                            // inline bn1 finalize
        float mean = st[tid] * (1.0f / 32768.0f);
        float var = st[128 + tid] * (1.0f / 32768.0f) - mean * mean;
        float sc = bng[tid] / sqrtf(fmaxf(var, 0.0f) + EPS_);
        scsh[tid] = sc;
        scsh[128 + tid] = bnb[tid] - mean * sc;
    }
    __syncthreads();

    for (int i = tid; i < 32 * 128; i += 256) {
        int ml = i >> 7, o = i & 127;
        float4 v = *(const float4*)(h + (size_t)(m0 + ml) * 512 + o * 4);
        float sc = scsh[o], sh = scsh[128 + o];
        float r = fmaxf(fmaxf(v.x * sc + sh, v.y * sc + sh),
                        fmaxf(v.z * sc + sh, v.w * sc + sh));
        hs[ml * 128 + o] = r;
        out[(size_t)OUT_FEAT + (size_t)(m0 + ml) * 128 + o] = r;
    }
    __syncthreads();

    int o = tid & 127, gr = tid >> 7;
    int mbase = gr * 16;
    float acc[3][16];
    {
        float bb0 = b1[o], bb1 = b2[o], bb2 = b3[o];
        #pragma unroll
        for (int mm = 0; mm < 16; mm++) {
            acc[0][mm] = bb0; acc[1][mm] = bb1; acc[2][mm] = bb2;
        }
    }
    for (int c4 = 0; c4 < 32; c4++) {
        float4 w1v = wp[c4 * 128 + o];          // coalesced 16B/lane
        float4 w2v = wp[4096 + c4 * 128 + o];
        float4 w3v = wp[8192 + c4 * 128 + o];
        const float* hp = &hs[mbase * 128 + c4 * 4];
        #pragma unroll
        for (int mm = 0; mm < 16; mm++) {
            float4 hv = *(const float4*)(hp + mm * 128);   // wave-uniform broadcast
            acc[0][mm] += w1v.x * hv.x; acc[0][mm] += w1v.y * hv.y;
            acc[0][mm] += w1v.z * hv.z; acc[0][mm] += w1v.w * hv.w;
            acc[1][mm] += w2v.x * hv.x; acc[1][mm] += w2v.y * hv.y;
            acc[1][mm] += w2v.z * hv.z; acc[1][mm] += w2v.w * hv.w;
            acc[2][mm] += w3v.x * hv.x; acc[2][mm] += w3v.y * hv.y;
            acc[2][mm] += w3v.z * hv.z; acc[2][mm] += w3v.w * hv.w;
        }
    }
    __syncthreads();                            // all hs reads done; reuse as scratch
    float psum[3], psq[3];
    #pragma unroll
    for (int k = 0; k < 3; k++) {
        float s = 0.0f, sq = 0.0f;
        float* yk = y + (size_t)k * M_ * 128;
        #pragma unroll
        for (int mm = 0; mm < 16; mm++) {
            float v = acc[k][mm];
            yk[(size_t)(m0 + mbase + mm) * 128 + o] = v;
            s += v; sq += v * v;
        }
        psum[k] = s; psq[k] = sq;
    }
    #pragma unroll
    for (int k = 0; k < 3; k++) {
        hs[(k * 2 + gr) * 128 + o] = psum[k];
        hs[768 + (k * 2 + gr) * 128 + o] = psq[k];
    }
    __syncthreads();
    for (int t = tid; t < 384; t += 256) {      // strided: 384 items, 256 threads
        int k = t >> 7, oo = t & 127;
        float s  = hs[(k * 2) * 128 + oo] + hs[(k * 2 + 1) * 128 + oo];
        float sq = hs[768 + (k * 2) * 128 + oo] + hs[768 + (k * 2 + 1) * 128 + oo];
        int base = 512 + k * 512;
        atomicAdd(&st[base + oo], s);
        atomicAdd(&st[base + 128 + oo], sq);
    }
}

// 256 WG x 256 (4 waves, 8 rows/wave). Inline branch-BN finalize, bn+relu,
// head matmuls, 7 fp32 outputs per row.
__global__ __launch_bounds__(256) void k_heads(const float* __restrict__ y,
                                               const float* __restrict__ st,
                                               const float* __restrict__ wce, const float* __restrict__ bce,
                                               const float* __restrict__ wlwh, const float* __restrict__ blwh,
                                               const float* __restrict__ wth, const float* __restrict__ bth,
                                               const float* __restrict__ bng, const float* __restrict__ bnb,
                                               float* __restrict__ out) {
    int tid = threadIdx.x;
    __shared__ float bsc[768];                  // k*256 + [0..127]=scale, [128..255]=shift
    for (int t = tid; t < 384; t += 256) {
        int k = t >> 7, o = t & 127;
        int base = 512 + k * 512;
        float mean = st[base + o] * (1.0f / 8192.0f);
        float var = st[base + 128 + o] * (1.0f / 8192.0f) - mean * mean;
        float sc = bng[o] / sqrtf(fmaxf(var, 0.0f) + EPS_);
        bsc[k * 256 + o] = sc;
        bsc[k * 256 + 128 + o] = bnb[o] - mean * sc;
    }
    __syncthreads();

    int wave = tid >> 6, lane = tid & 63;
    const float* y1 = y;
    const float* y2 = y + (size_t)M_ * D_;
    const float* y3 = y + 2 * (size_t)M_ * D_;
    #pragma unroll 2
    for (int i = 0; i < 8; i++) {
        int m = blockIdx.x * 32 + wave * 8 + i;
        float p[7] = {0, 0, 0, 0, 0, 0, 0};
        #pragma unroll
        for (int cc = 0; cc < 2; cc++) {
            int c = lane + 64 * cc;
            float v1 = fmaxf(y1[(size_t)m * D_ + c] * bsc[c] + bsc[128 + c], 0.0f);
            float v2 = fmaxf(y2[(size_t)m * D_ + c] * bsc[256 + c] + bsc[384 + c], 0.0f);
            float v3 = fmaxf(y3[(size_t)m * D_ + c] * bsc[512 + c] + bsc[640 + c], 0.0f);
            p[0] += v1 * wce[c];
            p[1] += v1 * wce[128 + c];
            p[2] += v1 * wce[256 + c];
            p[3] += v2 * wlwh[c];
            p[4] += v2 * wlwh[128 + c];
            p[5] += v2 * wlwh[256 + c];
            p[6] += v3 * wth[c];
        }
        #pragma unroll
        for (int off = 32; off > 0; off >>= 1) {
            #pragma unroll
            for (int j = 0; j < 7; j++) p[j] += __shfl_xor(p[j], off);
        }
        if (lane == 0) {
            out[m * 7 + 0] = p[0] + bce[0];
            out[m * 7 + 1] = p[1] + bce[1];
            out[m * 7 + 2] = p[2] + bce[2];
            out[m * 7 + 3] = p[3] + blwh[0];
            out[m * 7 + 4] = p[4] + blwh[1];
            out[m * 7 + 5] = p[5] + blwh[2];
            out[m * 7 + 6] = p[6] + bth[0];
        }
    }
}

extern "C" void kernel_launch(void* const* d_in, const int* in_sizes, int n_in,
                              void* d_out, int out_size, void* d_ws, size_t ws_size,
                              hipStream_t stream) {
    (void)in_sizes; (void)n_in; (void)out_size; (void)ws_size;
    const float* x        = (const float*)d_in[0];
    const float* conv1_w  = (const float*)d_in[1];
    const float* conv1_b  = (const float*)d_in[2];
    const float* bn_g     = (const float*)d_in[3];
    const float* bn_b     = (const float*)d_in[4];
    const float* fc1_w    = (const float*)d_in[5];
    const float* fc1_b    = (const float*)d_in[6];
    const float* fc_ce_w  = (const float*)d_in[7];
    const float* fc_ce_b  = (const float*)d_in[8];
    const float* fc2_w    = (const float*)d_in[9];
    const float* fc2_b    = (const float*)d_in[10];
    const float* fc_lwh_w = (const float*)d_in[11];
    const float* fc_lwh_b = (const float*)d_in[12];
    const float* fc3_w    = (const float*)d_in[13];
    const float* fc3_b    = (const float*)d_in[14];
    const float* fc_th_w  = (const float*)d_in[15];
    const float* fc_th_b  = (const float*)d_in[16];

    float* ws = (float*)d_ws;
    float* h  = ws + H_OFF;
    float* y  = ws + Y_OFF;
    float* st = ws + ST_OFF;
    float4* wp  = (float4*)(ws + WP_OFF);
    float4* pk4 = (float4*)(ws + PK_OFF);
    float* out = (float*)d_out;

    hipLaunchKernelGGL(k_prep,     dim3(144), dim3(256), 0, stream,
                       x, fc1_w, fc2_w, fc3_w, st, wp, pk4);
    hipLaunchKernelGGL(k_ballconv, dim3(512), dim3(256), 0, stream,
                       x, conv1_w, conv1_b, pk4, h);
    hipLaunchKernelGGL(k_bn1stats, dim3(256), dim3(512), 0, stream, h, st);
    hipLaunchKernelGGL(k_fc,       dim3(256), dim3(256), 0, stream, h, st, wp,
                       fc1_b, fc2_b, fc3_b, bn_g, bn_b, y, out);
    hipLaunchKernelGGL(k_heads,    dim3(256), dim3(256), 0, stream, y, st,
                       fc_ce_w, fc_ce_b, fc_lwh_w, fc_lwh_b, fc_th_w, fc_th_b, bn_g, bn_b, out);
}

// Round 8
// 189.314 us; speedup vs baseline: 1.6226x; 1.0055x over previous
//
#include <hip/hip_runtime.h>

#define B_   2
#define T_   5
#define N_   4096
#define C_   16
#define D_   128
#define S_   4
#define NS_  16384   // (T-1)*N
#define M_   8192    // B*N
#define EPS_ 1e-5f

// ---- ws layout (fp32 element offsets) ----
#define H_OFF   0u          // h: M*512 = 4194304
#define Y_OFF   4194304u    // y: 3*M*128 = 3145728
#define ST_OFF  7340032u    // stats: 2048 floats
#define WP_OFF  7342080u    // packed transposed FC weights: 3*16384 floats
#define PK_OFF  7391232u    // SoA scan data: 2*16384 float4 = 131072 floats
// st: [0..127] sum_h, [128..255] sumsq_h; branch k: 512+k*512 (+0 sum, +128 sumsq)

#define OUT_FEAT 57344      // element offset of feature within d_out (fp32)

// 144 WGs x 256. WGs [0,128): build pk4[b][j] = (px,py,pz,|p|^2) — SoA scan pack.
// WGs [128,144): pack FC weights into transposed float4 layout; WG 128 zeros st.
__global__ __launch_bounds__(256) void k_prep(const float* __restrict__ x,
                                              const float* __restrict__ fw1,
                                              const float* __restrict__ fw2,
                                              const float* __restrict__ fw3,
                                              float* __restrict__ st,
                                              float4* __restrict__ wp,
                                              float4* __restrict__ pk4) {
    int tid = threadIdx.x;
    if (blockIdx.x < 128) {
        int row = blockIdx.x * 256 + tid;       // 0..32767
        int b = row >> 14, j = row & 16383;
        const float* p = x + (size_t)b * (T_ * N_ * C_) + N_ * C_ + (size_t)j * 16;
        float4 v = *(const float4*)p;
        float pn = (v.x * v.x + v.y * v.y) + v.z * v.z;   // same expr as scan
        pk4[row] = make_float4(v.x, v.y, v.z, pn);
        return;
    }
    int pb = blockIdx.x - 128;                  // 0..15
    if (pb == 0) {
        #pragma unroll
        for (int i = 0; i < 8; i++) st[tid + 256 * i] = 0.0f;
    }
    int idx = pb * 256 + tid;                   // 0..4095 float4s per FC
    int o = idx >> 5, c4 = idx & 31;
    const float* fws[3] = { fw1, fw2, fw3 };
    #pragma unroll
    for (int k = 0; k < 3; k++)
        wp[k * 4096 + c4 * 128 + o] = *(const float4*)(fws[k] + o * 128 + c4 * 4);
}

// 2048 WGs x 256 = 8192 waves, ONE query per wave (max TLP, stragglers don't
// stack). Ball query scans SoA pk4 (16B/lane coalesced, 8 loads/512-pt chunk);
// gathered rows via wave-uniform broadcast loads; conv1 in registers. No barriers.
__global__ __launch_bounds__(256) void k_ballconv(const float* __restrict__ x,
                                                  const float* __restrict__ w,
                                                  const float* __restrict__ bias,
                                                  const float4* __restrict__ pk4,
                                                  float* __restrict__ h) {
    int tid = threadIdx.x;
    int wid = tid >> 6, lane = tid & 63;
    float wc0[16], wc1[16];                     // conv1 rows lane, lane+64
    #pragma unroll
    for (int j = 0; j < 4; j++) {
        float4 a = *(const float4*)(w + lane * 16 + j * 4);
        float4 b2 = *(const float4*)(w + (lane + 64) * 16 + j * 4);
        wc0[j*4+0] = a.x;  wc0[j*4+1] = a.y;  wc0[j*4+2] = a.z;  wc0[j*4+3] = a.w;
        wc1[j*4+0] = b2.x; wc1[j*4+1] = b2.y; wc1[j*4+2] = b2.z; wc1[j*4+3] = b2.w;
    }
    float bo0 = bias[lane], bo1 = bias[lane + 64];

    int m = blockIdx.x * 4 + wid;
    int b = m >> 12, q = m & (N_ - 1);
    const float* xb = x + (size_t)b * (T_ * N_ * C_);
    const float* pts = xb + N_ * C_;            // 16384 rows of 16
    const float4* pk = pk4 + b * 16384;
    float qx = xb[q * 16 + 0];
    float qy = xb[q * 16 + 1];
    float qz = xb[q * 16 + 2];
    float qn = (qx * qx + qy * qy) + qz * qz;

    int ids[4] = {0, 0, 0, 0};
    int cnt = 0;
    for (int it = 0; it < 32 && cnt < 4; it++) {
        int base = it * 512;
        float4 pv[8];
        #pragma unroll
        for (int u = 0; u < 8; u++)             // 8 independent coalesced loads
            pv[u] = pk[base + u * 64 + lane];
        unsigned long long mk[8];
        #pragma unroll
        for (int u = 0; u < 8; u++) {
            float dot = (qx * pv[u].x + qy * pv[u].y) + qz * pv[u].z;
            mk[u] = __ballot((qn + pv[u].w) - 2.0f * dot < 1.0f);  // ref form
        }
        #pragma unroll
        for (int u = 0; u < 8; u++) {
            unsigned long long mask = mk[u];
            while (mask && cnt < 4) {           // wave-uniform scalar loop
                ids[cnt] = base + u * 64 + __builtin_ctzll(mask);
                cnt++;
                mask &= (mask - 1);
            }
        }
    }
    if (cnt >= 1) {                             // duplicate-first fill
        #pragma unroll
        for (int s = 1; s < 4; s++) if (cnt <= s) ids[s] = ids[0];
    }

    float a0[4], a1[4];
    #pragma unroll
    for (int s = 0; s < 4; s++) {               // wave-uniform rows: broadcast loads
        const float* rp = pts + (size_t)ids[s] * 16;
        float4 r0 = *(const float4*)(rp);
        float4 r1 = *(const float4*)(rp + 4);
        float4 r2 = *(const float4*)(rp + 8);
        float4 r3 = *(const float4*)(rp + 12);
        float s0 = bo0, s1 = bo1;
        s0 += wc0[0] * r0.x;  s0 += wc0[1] * r0.y;  s0 += wc0[2] * r0.z;  s0 += wc0[3] * r0.w;
        s0 += wc0[4] * r1.x;  s0 += wc0[5] * r1.y;  s0 += wc0[6] * r1.z;  s0 += wc0[7] * r1.w;
        s0 += wc0[8] * r2.x;  s0 += wc0[9] * r2.y;  s0 += wc0[10] * r2.z; s0 += wc0[11] * r2.w;
        s0 += wc0[12] * r3.x; s0 += wc0[13] * r3.y; s0 += wc0[14] * r3.z; s0 += wc0[15] * r3.w;
        s1 += wc1[0] * r0.x;  s1 += wc1[1] * r0.y;  s1 += wc1[2] * r0.z;  s1 += wc1[3] * r0.w;
        s1 += wc1[4] * r1.x;  s1 += wc1[5] * r1.y;  s1 += wc1[6] * r1.z;  s1 += wc1[7] * r1.w;
        s1 += wc1[8] * r2.x;  s1 += wc1[9] * r2.y;  s1 += wc1[10] * r2.z; s1 += wc1[11] * r2.w;
        s1 += wc1[12] * r3.x; s1 += wc1[13] * r3.y; s1 += wc1[14] * r3.z; s1 += wc1[15] * r3.w;
        a0[s] = s0; a1[s] = s1;
    }
    if (cnt == 0) {                             // empty query: grouped = 0 -> bias
        #pragma unroll
        for (int s = 0; s < 4; s++) { a0[s] = bo0; a1[s] = bo1; }
    }
    float* hrow = h + (size_t)m * 512;
    *(float4*)(hrow + lane * 4)       = make_float4(a0[0], a0[1], a0[2], a0[3]);
    *(float4*)(hrow + 256 + lane * 4) = make_float4(a1[0], a1[1], a1[2], a1[3]);
}

// 512 WG x 512: per-channel sum/sumsq of h over (m,s); coalesced, 4-way ILP.
__global__ __launch_bounds__(512) void k_bn1stats(const float* __restrict__ h,
                                                  float* __restrict__ st) {
    int t = threadIdx.x;
    float sum = 0.0f, sq = 0.0f;
    for (int m0 = blockIdx.x * 4; m0 < M_; m0 += gridDim.x * 4) {
        #pragma unroll
        for (int j = 0; j < 4; j++) {
            float v = h[(size_t)(m0 + j) * 512 + t];
            sum += v; sq += v * v;
        }
    }
    __shared__ float sm[512];
    sm[t] = sum;
    __syncthreads();
    if (t < 128) atomicAdd(&st[t], sm[4 * t] + sm[4 * t + 1] + sm[4 * t + 2] + sm[4 * t + 3]);
    __syncthreads();
    sm[t] = sq;
    __syncthreads();
    if (t < 128) atomicAdd(&st[128 + t], sm[4 * t] + sm[4 * t + 1] + sm[4 * t + 2] + sm[4 * t + 3]);
}

// 512 WG x 256, m-tile 16 (2 WG/CU -> 8 waves/CU). Inline bn1 finalize,
// bn1+max -> LDS (+ feature out), 3x 128x128 FC with coalesced packed weights
// + LDS-broadcast h, y write + branch-BN stats (LDS pre-reduce + atomics).
__global__ __launch_bounds__(256) void k_fc(const float* __restrict__ h,
                                            float* __restrict__ st,
                                            const float4* __restrict__ wp,
                                            const float* __restrict__ b1,
                                            const float* __restrict__ b2,
                                            const float* __restrict__ b3,
                                            const float* __restrict__ bng,
                                            const float* __restrict__ bnb,
                                            float* __restrict__ y,
                                            float* __restrict__ out) {
    int tid = threadIdx.x;
    int m0 = blockIdx.x * 16;
    __shared__ float hs[2048];                  // 16x128 staging, then stats scratch
    __shared__ float scsh[256];                 // [0..127] scale1, [128..255] shift1

    if (tid < 128) {                            // inline bn1 finalize
        float mean = st[tid] * (1.0f / 32768.0f);
        float var = st[128 + tid] * (1.0f / 32768.0f) - mean * mean;
        float sc = bng[tid] / sqrtf(fmaxf(var, 0.0f) + EPS_);
        scsh[tid] = sc;
        scsh[128 + tid] = bnb[tid] - mean * sc;
    }
    __syncthreads();

    for (int i = tid; i < 16 * 128; i += 256) {
        int ml = i >> 7, o = i & 127;
        float4 v = *(const float4*)(h + (size_t)(m0 + ml) * 512 + o * 4);
        float sc = scsh[o], sh = scsh[128 + o];
        float r = fmaxf(fmaxf(v.x * sc + sh, v.y * sc + sh),
                        fmaxf(v.z * sc + sh, v.w * sc + sh));
        hs[ml * 128 + o] = r;
        out[(size_t)OUT_FEAT + (size_t)(m0 + ml) * 128 + o] = r;
    }
    __syncthreads();

    int o = tid & 127, gr = tid >> 7;
    int mbase = gr * 8;
    float acc[3][8];
    {
        float bb0 = b1[o], bb1 = b2[o], bb2 = b3[o];
        #pragma unroll
        for (int mm = 0; mm < 8; mm++) {
            acc[0][mm] = bb0; acc[1][mm] = bb1; acc[2][mm] = bb2;
        }
    }
    for (int c4 = 0; c4 < 32; c4++) {
        float4 w1v = wp[c4 * 128 + o];          // coalesced 16B/lane, L2-warm
        float4 w2v = wp[4096 + c4 * 128 + o];
        float4 w3v = wp[8192 + c4 * 128 + o];
        const float* hp = &hs[mbase * 128 + c4 * 4];
        #pragma unroll
        for (int mm = 0; mm < 8; mm++) {
            float4 hv = *(const float4*)(hp + mm * 128);   // wave-uniform broadcast
            acc[0][mm] += w1v.x * hv.x; acc[0][mm] += w1v.y * hv.y;
            acc[0][mm] += w1v.z * hv.z; acc[0][mm] += w1v.w * hv.w;
            acc[1][mm] += w2v.x * hv.x; acc[1][mm] += w2v.y * hv.y;
            acc[1][mm] += w2v.z * hv.z; acc[1][mm] += w2v.w * hv.w;
            acc[2][mm] += w3v.x * hv.x; acc[2][mm] += w3v.y * hv.y;
            acc[2][mm] += w3v.z * hv.z; acc[2][mm] += w3v.w * hv.w;
        }
    }
    __syncthreads();                            // hs reads done; reuse as scratch
    float psum[3], psq[3];
    #pragma unroll
    for (int k = 0; k < 3; k++) {
        float s = 0.0f, sq = 0.0f;
        float* yk = y + (size_t)k * M_ * 128;
        #pragma unroll
        for (int mm = 0; mm < 8; mm++) {
            float v = acc[k][mm];
            yk[(size_t)(m0 + mbase + mm) * 128 + o] = v;
            s += v; sq += v * v;
        }
        psum[k] = s; psq[k] = sq;
    }
    #pragma unroll
    for (int k = 0; k < 3; k++) {
        hs[(k * 2 + gr) * 128 + o] = psum[k];          // [0,768)
        hs[768 + (k * 2 + gr) * 128 + o] = psq[k];     // [768,1536)
    }
    __syncthreads();
    for (int t = tid; t < 384; t += 256) {      // strided: 384 items, 256 threads
        int k = t >> 7, oo = t & 127;
        float s  = hs[(k * 2) * 128 + oo] + hs[(k * 2 + 1) * 128 + oo];
        float sq = hs[768 + (k * 2) * 128 + oo] + hs[768 + (k * 2 + 1) * 128 + oo];
        int base = 512 + k * 512;
        atomicAdd(&st[base + oo], s);
        atomicAdd(&st[base + 128 + oo], sq);
    }
}

// 512 WG x 256 (4 waves, 4 rows/wave, unrolled for load ILP). Inline branch-BN
// finalize, bn+relu, head matmuls, 7 fp32 outputs per row.
__global__ __launch_bounds__(256) void k_heads(const float* __restrict__ y,
                                               const float* __restrict__ st,
                                               const float* __restrict__ wce, const float* __restrict__ bce,
                                               const float* __restrict__ wlwh, const float* __restrict__ blwh,
                                               const float* __restrict__ wth, const float* __restrict__ bth,
                                               const float* __restrict__ bng, const float* __restrict__ bnb,
                                               float* __restrict__ out) {
    int tid = threadIdx.x;
    __shared__ float bsc[768];                  // k*256 + [0..127]=scale, [128..255]=shift
    for (int t = tid; t < 384; t += 256) {
        int k = t >> 7, o = t & 127;
        int base = 512 + k * 512;
        float mean = st[base + o] * (1.0f / 8192.0f);
        float var = st[base + 128 + o] * (1.0f / 8192.0f) - mean * mean;
        float sc = bng[o] / sqrtf(fmaxf(var, 0.0f) + EPS_);
        bsc[k * 256 + o] = sc;
        bsc[k * 256 + 128 + o] = bnb[o] - mean * sc;
    }
    __syncthreads();

    int wave = tid >> 6, lane = tid & 63;
    const float* y1 = y;
    const float* y2 = y + (size_t)M_ * D_;
    const float* y3 = y + 2 * (size_t)M_ * D_;
    #pragma unroll
    for (int i = 0; i < 4; i++) {               // independent rows: loads overlap
        int m = blockIdx.x * 16 + wave * 4 + i;
        float p[7] = {0, 0, 0, 0, 0, 0, 0};
        #pragma unroll
        for (int cc = 0; cc < 2; cc++) {
            int c = lane + 64 * cc;
            float v1 = fmaxf(y1[(size_t)m * D_ + c] * bsc[c] + bsc[128 + c], 0.0f);
            float v2 = fmaxf(y2[(size_t)m * D_ + c] * bsc[256 + c] + bsc[384 + c], 0.0f);
            float v3 = fmaxf(y3[(size_t)m * D_ + c] * bsc[512 + c] + bsc[640 + c], 0.0f);
            p[0] += v1 * wce[c];
            p[1] += v1 * wce[128 + c];
            p[2] += v1 * wce[256 + c];
            p[3] += v2 * wlwh[c];
            p[4] += v2 * wlwh[128 + c];
            p[5] += v2 * wlwh[256 + c];
            p[6] += v3 * wth[c];
        }
        #pragma unroll
        for (int off = 32; off > 0; off >>= 1) {
            #pragma unroll
            for (int j = 0; j < 7; j++) p[j] += __shfl_xor(p[j], off);
        }
        if (lane == 0) {
            out[m * 7 + 0] = p[0] + bce[0];
            out[m * 7 + 1] = p[1] + bce[1];
            out[m * 7 + 2] = p[2] + bce[2];
            out[m * 7 + 3] = p[3] + blwh[0];
            out[m * 7 + 4] = p[4] + blwh[1];
            out[m * 7 + 5] = p[5] + blwh[2];
            out[m * 7 + 6] = p[6] + bth[0];
        }
    }
}

extern "C" void kernel_launch(void* const* d_in, const int* in_sizes, int n_in,
                              void* d_out, int out_size, void* d_ws, size_t ws_size,
                              hipStream_t stream) {
    (void)in_sizes; (void)n_in; (void)out_size; (void)ws_size;
    const float* x        = (const float*)d_in[0];
    const float* conv1_w  = (const float*)d_in[1];
    const float* conv1_b  = (const float*)d_in[2];
    const float* bn_g     = (const float*)d_in[3];
    const float* bn_b     = (const float*)d_in[4];
    const float* fc1_w    = (const float*)d_in[5];
    const float* fc1_b    = (const float*)d_in[6];
    const float* fc_ce_w  = (const float*)d_in[7];
    const float* fc_ce_b  = (const float*)d_in[8];
    const float* fc2_w    = (const float*)d_in[9];
    const float* fc2_b    = (const float*)d_in[10];
    const float* fc_lwh_w = (const float*)d_in[11];
    const float* fc_lwh_b = (const float*)d_in[12];
    const float* fc3_w    = (const float*)d_in[13];
    const float* fc3_b    = (const float*)d_in[14];
    const float* fc_th_w  = (const float*)d_in[15];
    const float* fc_th_b  = (const float*)d_in[16];

    float* ws = (float*)d_ws;
    float* h  = ws + H_OFF;
    float* y  = ws + Y_OFF;
    float* st = ws + ST_OFF;
    float4* wp  = (float4*)(ws + WP_OFF);
    float4* pk4 = (float4*)(ws + PK_OFF);
    float* out = (float*)d_out;

    hipLaunchKernelGGL(k_prep,     dim3(144),  dim3(256), 0, stream,
                       x, fc1_w, fc2_w, fc3_w, st, wp, pk4);
    hipLaunchKernelGGL(k_ballconv, dim3(2048), dim3(256), 0, stream,
                       x, conv1_w, conv1_b, pk4, h);
    hipLaunchKernelGGL(k_bn1stats, dim3(512),  dim3(512), 0, stream, h, st);
    hipLaunchKernelGGL(k_fc,       dim3(512),  dim3(256), 0, stream, h, st, wp,
                       fc1_b, fc2_b, fc3_b, bn_g, bn_b, y, out);
    hipLaunchKernelGGL(k_heads,    dim3(512),  dim3(256), 0, stream, y, st,
                       fc_ce_w, fc_ce_b, fc_lwh_w, fc_lwh_b, fc_th_w, fc_th_b, bn_g, bn_b, out);
}